// Round 3
// baseline (19295.621 us; speedup 1.0000x reference)
//
#include <hip/hip_runtime.h>
#include <stddef.h>
#include <math.h>

static constexpr int B = 64, P = 196, ED = 2048, AD = 512, DD = 512, E = 300, V = 1000, T = 96, TD = 95;
static constexpr int KX = E + ED;      // 2348
static constexpr int KTOT = KX + DD;   // 2860
static constexpr int KSPLIT = 8;
static constexpr int KPER = 368;       // 23 tiles of 16; 8*368 = 2944 >= 2860
static constexpr int NG = 4 * DD;      // 2048

// d_out layout (all float32): predictions (B,TD,V), caps (B,T), decode_lengths (B),
// alphas (B,TD,P), sort_ind (B)
static constexpr size_t POFF   = 0;
static constexpr size_t CAPOFF = (size_t)B * TD * V;
static constexpr size_t DLOFF  = CAPOFF + (size_t)B * T;
static constexpr size_t AOFF   = DLOFF + B;
static constexpr size_t SOFF   = AOFF + (size_t)B * TD * P;

__device__ __forceinline__ float sigm(float x) { return 1.0f / (1.0f + expf(-x)); }

// ---------------------------------------------------------------------------
// K0: stable descending sort by length + gather caps + write int-ish outputs
// ---------------------------------------------------------------------------
__global__ __launch_bounds__(64) void k_sort(const int* __restrict__ lens,
                                             const int* __restrict__ caps_in,
                                             int* __restrict__ sidx,
                                             int* __restrict__ dlen,
                                             int* __restrict__ caps_s,
                                             float* __restrict__ out) {
    __shared__ int sl[B];
    __shared__ int ss[B];
    int i = threadIdx.x;
    sl[i] = lens[i];
    __syncthreads();
    int li = sl[i];
    int r = 0;
    for (int j = 0; j < B; j++) {
        int lj = sl[j];
        r += (lj > li) || (lj == li && j < i);
    }
    ss[r] = i;
    sidx[r] = i;
    dlen[r] = li - 1;
    out[DLOFF + r] = (float)(li - 1);
    out[SOFF + r] = (float)i;
    __syncthreads();
    for (int idx = i; idx < B * T; idx += B) {
        int b = idx / T, tt = idx % T;
        int v = caps_in[ss[b] * T + tt];
        caps_s[idx] = v;
        out[CAPOFF + idx] = (float)v;
    }
}

// ---------------------------------------------------------------------------
// kE: precompute ALL timestep embedding gathers: embT[(t*E + k)*B + b]
// ---------------------------------------------------------------------------
__global__ __launch_bounds__(256) void k_emball(const float* __restrict__ emb,
                                                const int* __restrict__ caps_s,
                                                float* __restrict__ embT) {
    int t = blockIdx.x;
    int k0 = blockIdx.y * 60;
    for (int l = threadIdx.x; l < 60 * 64; l += 256) {
        int r = l >> 6, b = l & 63;
        int k = k0 + r;
        int cap = caps_s[b * T + t];
        embT[((size_t)t * E + k) * B + b] = emb[(size_t)cap * E + k];
    }
}

// ---------------------------------------------------------------------------
// K1: mean over P of sorted encoder_out -> mean_eo (B, ED)
// ---------------------------------------------------------------------------
__global__ __launch_bounds__(256) void k_mean(const float* __restrict__ eo,
                                              const int* __restrict__ sidx,
                                              float* __restrict__ mean_eo) {
    int b = blockIdx.y;
    int d = blockIdx.x * 256 + threadIdx.x;
    const float* base = eo + ((size_t)sidx[b] * P) * ED + d;
    float s = 0.f;
    for (int p = 0; p < P; p++) s += base[(size_t)p * ED];
    mean_eo[(size_t)b * ED + d] = s * (1.0f / (float)P);
}

// ---------------------------------------------------------------------------
// K2: h0/c0 init; c0 -> cb1 (c(-1) lives in parity buffer 1); seeds xT h-rows
// ---------------------------------------------------------------------------
__global__ __launch_bounds__(256) void k_init(const float* __restrict__ mean_eo,
                                              const float* __restrict__ Wh, const float* __restrict__ bh,
                                              const float* __restrict__ Wc, const float* __restrict__ bc,
                                              float* __restrict__ h0, float* __restrict__ c0,
                                              float* __restrict__ xT) {
    int idx = blockIdx.x * 256 + threadIdx.x;  // B*DD
    int b = idx >> 9, j = idx & 511;
    const float* m = mean_eo + (size_t)b * ED;
    float ah = bh[j], ac = bc[j];
    for (int k = 0; k < ED; k++) {
        float mv = m[k];
        ah += mv * Wh[(size_t)k * DD + j];
        ac += mv * Wc[(size_t)k * DD + j];
    }
    h0[idx] = ah;
    c0[idx] = ac;
    xT[(size_t)(KX + j) * B + b] = ah;
}

// ---------------------------------------------------------------------------
// K3: att1[m,n] = eo_sorted[m,:] @ W_enc_att[:,n] + b   (row-major, B*P x AD)
// ---------------------------------------------------------------------------
__global__ __launch_bounds__(256) void k_att1(const float* __restrict__ eo,
                                              const float* __restrict__ W,
                                              const float* __restrict__ bias,
                                              const int* __restrict__ sidx,
                                              float* __restrict__ att1) {
    int m0 = blockIdx.x * 64, n0 = blockIdx.y * 64;
    __shared__ float sA[16][68];
    __shared__ float sB[16][68];
    int tid = threadIdx.x;
    int tx = tid & 15, ty = tid >> 4;
    float acc[4][4] = {};

    int la_m = tid >> 2;
    int la_k = (tid & 3) * 4;
    int lb_k = tid >> 4;
    int lb_n = (tid & 15) * 4;

    int mA = m0 + la_m;
    int bA = mA / P, pA = mA % P;
    const float* arow = eo + ((size_t)sidx[bA] * P + pA) * ED;

    for (int k0 = 0; k0 < ED; k0 += 16) {
        float4 av = *(const float4*)(arow + k0 + la_k);
        sA[la_k + 0][la_m] = av.x;
        sA[la_k + 1][la_m] = av.y;
        sA[la_k + 2][la_m] = av.z;
        sA[la_k + 3][la_m] = av.w;
        float4 bv = *(const float4*)(W + (size_t)(k0 + lb_k) * AD + n0 + lb_n);
        *(float4*)&sB[lb_k][lb_n] = bv;
        __syncthreads();
#pragma unroll
        for (int kk = 0; kk < 16; kk++) {
            float4 a4 = *(const float4*)&sA[kk][ty * 4];
            float4 b4 = *(const float4*)&sB[kk][tx * 4];
            float av_[4] = {a4.x, a4.y, a4.z, a4.w};
            float bv_[4] = {b4.x, b4.y, b4.z, b4.w};
#pragma unroll
            for (int i = 0; i < 4; i++)
#pragma unroll
                for (int j = 0; j < 4; j++) acc[i][j] += av_[i] * bv_[j];
        }
        __syncthreads();
    }
#pragma unroll
    for (int i = 0; i < 4; i++) {
        int m = m0 + ty * 4 + i;
        int n = n0 + tx * 4;
        float4 o;
        o.x = acc[i][0] + bias[n + 0];
        o.y = acc[i][1] + bias[n + 1];
        o.z = acc[i][2] + bias[n + 2];
        o.w = acc[i][3] + bias[n + 3];
        *(float4*)(att1 + (size_t)m * AD + n) = o;
    }
}

// ---------------------------------------------------------------------------
// kA2f: per-b block (64 x 1024). Phase A: LSTM cell for step t-1 (t>0) from
// part(t-1) -> h(t-1) into LDS + global (hseq, cbuf, xT h-rows). Phase B:
// att2 = h @ Wda + bda in-block (2-way k-split). Phase C: relu-dot + softmax.
// ---------------------------------------------------------------------------
__global__ __launch_bounds__(1024) void kA2f(const float* __restrict__ part,
                                             const float* __restrict__ bih,
                                             const float* __restrict__ bhh,
                                             const float* __restrict__ h0,
                                             const float* __restrict__ cread,
                                             float* __restrict__ cwrite,
                                             const float* __restrict__ Wda,
                                             const float* __restrict__ bda,
                                             const float* __restrict__ att1,
                                             const float* __restrict__ wf,
                                             const float* __restrict__ bfv,
                                             const int* __restrict__ dlen,
                                             float* __restrict__ alpha,
                                             float* __restrict__ xT,
                                             float* __restrict__ hseq,
                                             float* __restrict__ out, int t) {
    int b = blockIdx.x;
    int tid = threadIdx.x;
    __shared__ float sh[DD];
    __shared__ float swf[AD];
    __shared__ float sa2[AD];
    __shared__ float pa[2][AD];
    __shared__ float se[P];
    __shared__ float red[1024];

    // ---- Phase A: cell (t>0) or h0 load (t==0); lanes >=512 stage wf ----
    if (tid >= 512) {
        swf[tid - 512] = wf[tid - 512];
    } else {
        int j = tid;
        if (t == 0) {
            sh[j] = h0[(size_t)b * DD + j];
        } else {
            float gi = bih[j] + bhh[j];
            float gf = bih[DD + j] + bhh[DD + j];
            float gg = bih[2 * DD + j] + bhh[2 * DD + j];
            float go = bih[3 * DD + j] + bhh[3 * DD + j];
#pragma unroll
            for (int s = 0; s < KSPLIT; s++) {
                const float* pr = part + ((size_t)s * B + b) * NG;
                gi += pr[j];
                gf += pr[DD + j];
                gg += pr[2 * DD + j];
                go += pr[3 * DD + j];
            }
            const float* holds = (t == 1) ? h0 : (hseq + (size_t)(t - 2) * B * DD);
            float cold = cread[(size_t)b * DD + j];
            float hold = holds[(size_t)b * DD + j];
            float cnew = sigm(gf) * cold + sigm(gi) * tanhf(gg);
            float hnew = sigm(go) * tanhf(cnew);
            bool m = dlen[b] > (t - 1);
            float h2 = m ? hnew : hold;
            float c2 = m ? cnew : cold;
            sh[j] = h2;
            hseq[(size_t)(t - 1) * B * DD + (size_t)b * DD + j] = h2;
            cwrite[(size_t)b * DD + j] = c2;
            xT[(size_t)(KX + j) * B + b] = h2;
        }
    }
    __syncthreads();

    // ---- Phase B: att2 = sh @ Wda + bda (2-way k-split over 1024 thr) ----
    {
        int n = tid & 511, half = tid >> 9;
        int kb = half * 256;
        float acc = 0.f;
#pragma unroll 8
        for (int ki = 0; ki < 256; ki++)
            acc += sh[kb + ki] * Wda[(size_t)(kb + ki) * AD + n];
        pa[half][n] = acc;
    }
    __syncthreads();
    if (tid < 512) sa2[tid] = pa[0][tid] + pa[1][tid] + bda[tid];
    __syncthreads();

    // ---- Phase C: e = relu(att1 + att2)·wf + bf ; softmax ----
    int w = tid >> 6, lane = tid & 63;
    float bf0 = bfv[0];
#pragma unroll 2
    for (int p = w; p < P; p += 16) {
        const float* row = att1 + ((size_t)b * P + p) * AD + lane * 8;
        float4 u0 = *(const float4*)row;
        float4 u1 = *(const float4*)(row + 4);
        float4 s0 = *(const float4*)&sa2[lane * 8];
        float4 s1 = *(const float4*)&sa2[lane * 8 + 4];
        float4 w0 = *(const float4*)&swf[lane * 8];
        float4 w1 = *(const float4*)&swf[lane * 8 + 4];
        float acc = fmaxf(u0.x + s0.x, 0.f) * w0.x + fmaxf(u0.y + s0.y, 0.f) * w0.y +
                    fmaxf(u0.z + s0.z, 0.f) * w0.z + fmaxf(u0.w + s0.w, 0.f) * w0.w +
                    fmaxf(u1.x + s1.x, 0.f) * w1.x + fmaxf(u1.y + s1.y, 0.f) * w1.y +
                    fmaxf(u1.z + s1.z, 0.f) * w1.z + fmaxf(u1.w + s1.w, 0.f) * w1.w;
#pragma unroll
        for (int mm = 32; mm >= 1; mm >>= 1) acc += __shfl_xor(acc, mm, 64);
        if (lane == 0) se[p] = acc + bf0;
    }
    __syncthreads();

    red[tid] = (tid < P) ? se[tid] : -1e30f;
    __syncthreads();
    for (int s = 512; s > 0; s >>= 1) {
        if (tid < s) red[tid] = fmaxf(red[tid], red[tid + s]);
        __syncthreads();
    }
    float mx = red[0];
    __syncthreads();
    float ex = (tid < P) ? expf(se[tid] - mx) : 0.f;
    red[tid] = ex;
    __syncthreads();
    for (int s = 512; s > 0; s >>= 1) {
        if (tid < s) red[tid] += red[tid + s];
        __syncthreads();
    }
    float inv = 1.0f / red[0];
    if (tid < P) {
        float a = ex * inv;
        alpha[(size_t)b * P + tid] = a;
        float m = (dlen[b] > t) ? 1.f : 0.f;
        out[AOFF + ((size_t)b * TD + t) * P + tid] = a * m;
    }
}

// ---------------------------------------------------------------------------
// kBf: per (ch,b) block: fg slice = sigm(hprev@Wfb+bfb) in-block, then
// awe = eo·alpha (deep in-flight), xg = fg*awe -> xT rows [E, KX).
// 1-D grid 512, ch = bid&7 so each XCD's L2 pins one Wfb column slice.
// ---------------------------------------------------------------------------
__global__ __launch_bounds__(256) void kBf(const float* __restrict__ eo,
                                           const int* __restrict__ sidx,
                                           const float* __restrict__ hprev,
                                           const float* __restrict__ Wfb,
                                           const float* __restrict__ bfb,
                                           const float* __restrict__ alpha,
                                           float* __restrict__ xT) {
    int bid = blockIdx.x;
    int ch = bid & 7, b = bid >> 3;
    int tid = threadIdx.x;
    __shared__ float sh[DD];
    __shared__ float sal[P];
    __shared__ float sfg[256];
    __shared__ float partl[4][260];

    sh[tid] = hprev[(size_t)b * DD + tid];
    sh[tid + 256] = hprev[(size_t)b * DD + tid + 256];
    if (tid < P) sal[tid] = alpha[(size_t)b * P + tid];
    __syncthreads();

    // fg slice: d = ch*256 + tid
    {
        int d = ch * 256 + tid;
        float fgv = bfb[d];
#pragma unroll 8
        for (int k = 0; k < DD; k++) fgv += sh[k] * Wfb[(size_t)k * ED + d];
        sfg[tid] = sigm(fgv);
    }

    // awe: p split 4 ways across waves, float4 along d
    int pg = tid >> 6, lane = tid & 63;
    int d4 = ch * 256 + lane * 4;
    const float* base = eo + ((size_t)sidx[b] * P) * ED + d4;
    float ax = 0.f, ay = 0.f, az = 0.f, aw = 0.f;
#pragma unroll 7
    for (int i = 0; i < 49; i++) {
        int p = pg + i * 4;
        float4 v = *(const float4*)(base + (size_t)p * ED);
        float a = sal[p];
        ax += v.x * a; ay += v.y * a; az += v.z * a; aw += v.w * a;
    }
    partl[pg][lane * 4 + 0] = ax;
    partl[pg][lane * 4 + 1] = ay;
    partl[pg][lane * 4 + 2] = az;
    partl[pg][lane * 4 + 3] = aw;
    __syncthreads();
    if (tid < 64) {
        int d0 = ch * 256 + tid * 4;
        float s0 = partl[0][tid * 4 + 0] + partl[1][tid * 4 + 0] + partl[2][tid * 4 + 0] + partl[3][tid * 4 + 0];
        float s1 = partl[0][tid * 4 + 1] + partl[1][tid * 4 + 1] + partl[2][tid * 4 + 1] + partl[3][tid * 4 + 1];
        float s2 = partl[0][tid * 4 + 2] + partl[1][tid * 4 + 2] + partl[2][tid * 4 + 2] + partl[3][tid * 4 + 2];
        float s3 = partl[0][tid * 4 + 3] + partl[1][tid * 4 + 3] + partl[2][tid * 4 + 3] + partl[3][tid * 4 + 3];
        xT[(size_t)(E + d0 + 0) * B + b] = sfg[tid * 4 + 0] * s0;
        xT[(size_t)(E + d0 + 1) * B + b] = sfg[tid * 4 + 1] * s1;
        xT[(size_t)(E + d0 + 2) * B + b] = sfg[tid * 4 + 2] * s2;
        xT[(size_t)(E + d0 + 3) * B + b] = sfg[tid * 4 + 3] * s3;
    }
}

// ---------------------------------------------------------------------------
// kC: gates partial GEMM. grid 512 = 8 K-splits x 64 N-tiles(32 cols).
//     emb rows come from embT_t, xg/h rows from xT.
// ---------------------------------------------------------------------------
__global__ __launch_bounds__(256) void kC(const float* __restrict__ xT,
                                          const float* __restrict__ embT_t,
                                          const float* __restrict__ Wih,
                                          const float* __restrict__ Whh,
                                          float* __restrict__ part) {
    int bx = blockIdx.x;
    int ks = bx >> 6, nb = bx & 63;
    int n0 = nb * 32;
    int tid = threadIdx.x;
    int tb = tid & 15, tn = tid >> 4;
    __shared__ float sW[16][36];
    float acc[4][2] = {};
    int kbase = ks * KPER;

    for (int tile = 0; tile < 23; tile++) {
        int k0 = kbase + tile * 16;
        if (tid < 128) {
            int kk = tid >> 3, nn = (tid & 7) * 4;
            int kg = k0 + kk;
            float4 wv = make_float4(0.f, 0.f, 0.f, 0.f);
            if (kg < KX) wv = *(const float4*)&Wih[(size_t)kg * NG + n0 + nn];
            else if (kg < KTOT) wv = *(const float4*)&Whh[(size_t)(kg - KX) * NG + n0 + nn];
            *(float4*)&sW[kk][nn] = wv;
        }
        __syncthreads();
#pragma unroll
        for (int kk = 0; kk < 16; kk++) {
            int kg = k0 + kk;
            float4 xv = make_float4(0.f, 0.f, 0.f, 0.f);
            if (kg < E) xv = *(const float4*)&embT_t[(size_t)kg * B + tb * 4];
            else if (kg < KTOT) xv = *(const float4*)&xT[(size_t)kg * B + tb * 4];
            float w0 = sW[kk][tn * 2 + 0];
            float w1 = sW[kk][tn * 2 + 1];
            acc[0][0] += xv.x * w0; acc[0][1] += xv.x * w1;
            acc[1][0] += xv.y * w0; acc[1][1] += xv.y * w1;
            acc[2][0] += xv.z * w0; acc[2][1] += xv.z * w1;
            acc[3][0] += xv.w * w0; acc[3][1] += xv.w * w1;
        }
        __syncthreads();
    }
    float* pr = part + (size_t)ks * B * NG;
#pragma unroll
    for (int i = 0; i < 4; i++)
#pragma unroll
        for (int j = 0; j < 2; j++) {
            int b = tb * 4 + i, n = n0 + tn * 2 + j;
            pr[(size_t)b * NG + n] = acc[i][j];
        }
}

// ---------------------------------------------------------------------------
// kD: trailing cell for the final step (t = TD-1): h(TD-1) -> hseq[TD-1]
// ---------------------------------------------------------------------------
__global__ __launch_bounds__(256) void kD(const float* __restrict__ part,
                                          const float* __restrict__ bih,
                                          const float* __restrict__ bhh,
                                          const float* __restrict__ hprev,
                                          const float* __restrict__ cc,
                                          const int* __restrict__ dlen,
                                          float* __restrict__ hseq_t,
                                          float* __restrict__ cn,
                                          int t) {
    int idx = blockIdx.x * 256 + threadIdx.x;  // B*DD
    int b = idx >> 9, j = idx & 511;
    float gi = bih[j] + bhh[j];
    float gf = bih[DD + j] + bhh[DD + j];
    float gg = bih[2 * DD + j] + bhh[2 * DD + j];
    float go = bih[3 * DD + j] + bhh[3 * DD + j];
#pragma unroll
    for (int s = 0; s < KSPLIT; s++) {
        const float* pr = part + ((size_t)s * B + b) * NG;
        gi += pr[j];
        gf += pr[DD + j];
        gg += pr[2 * DD + j];
        go += pr[3 * DD + j];
    }
    float cold = cc[idx], hold = hprev[idx];
    float cnew = sigm(gf) * cold + sigm(gi) * tanhf(gg);
    float hnew = sigm(go) * tanhf(cnew);
    bool m = dlen[b] > t;
    float h2 = m ? hnew : hold;
    float c2 = m ? cnew : cold;
    hseq_t[idx] = h2;
    cn[idx] = c2;
}

// ---------------------------------------------------------------------------
// K4: batched preds GEMM: out[b,t,v] = mask * (hseq[t,b,:]@Wfc + bfc)
// ---------------------------------------------------------------------------
__global__ __launch_bounds__(256) void k_predsall(const float* __restrict__ hseq,
                                                  const float* __restrict__ Wfc,
                                                  const float* __restrict__ bfc,
                                                  const int* __restrict__ dlen,
                                                  float* __restrict__ out) {
    int t = blockIdx.x;
    int n0 = blockIdx.y * 64;
    int tid = threadIdx.x;
    int tx = tid & 15, ty = tid >> 4;
    __shared__ float sA[16][68];
    __shared__ float sB[16][68];
    float acc[4][4] = {};
    const float* A = hseq + (size_t)t * B * DD;

    for (int k0 = 0; k0 < DD; k0 += 16) {
        {
            int b = tid >> 2, q = tid & 3;
            float4 hv = *(const float4*)(A + (size_t)b * DD + k0 + q * 4);
            sA[q * 4 + 0][b] = hv.x;
            sA[q * 4 + 1][b] = hv.y;
            sA[q * 4 + 2][b] = hv.z;
            sA[q * 4 + 3][b] = hv.w;
        }
        {
            int kk = tid >> 4, nn = (tid & 15) * 4;
            int c = n0 + nn;
            const float* wrow = Wfc + (size_t)(k0 + kk) * V;
            float4 wv;
            if (c + 3 < V) wv = *(const float4*)(wrow + c);
            else {
                wv.x = (c + 0 < V) ? wrow[c + 0] : 0.f;
                wv.y = (c + 1 < V) ? wrow[c + 1] : 0.f;
                wv.z = (c + 2 < V) ? wrow[c + 2] : 0.f;
                wv.w = (c + 3 < V) ? wrow[c + 3] : 0.f;
            }
            *(float4*)&sB[kk][nn] = wv;
        }
        __syncthreads();
#pragma unroll
        for (int kk = 0; kk < 16; kk++) {
            float4 a4 = *(const float4*)&sA[kk][ty * 4];
            float4 b4 = *(const float4*)&sB[kk][tx * 4];
            float av_[4] = {a4.x, a4.y, a4.z, a4.w};
            float bv_[4] = {b4.x, b4.y, b4.z, b4.w};
#pragma unroll
            for (int i = 0; i < 4; i++)
#pragma unroll
                for (int j = 0; j < 4; j++) acc[i][j] += av_[i] * bv_[j];
        }
        __syncthreads();
    }
#pragma unroll
    for (int i = 0; i < 4; i++) {
        int b = ty * 4 + i;
        bool m = dlen[b] > t;
#pragma unroll
        for (int j = 0; j < 4; j++) {
            int n = n0 + tx * 4 + j;
            if (n < V)
                out[POFF + ((size_t)b * TD + t) * V + n] = m ? (acc[i][j] + bfc[n]) : 0.f;
        }
    }
}

// ---------------------------------------------------------------------------
extern "C" void kernel_launch(void* const* d_in, const int* in_sizes, int n_in,
                              void* d_out, int out_size, void* d_ws, size_t ws_size,
                              hipStream_t stream) {
    const float* eo    = (const float*)d_in[0];
    const int*   caps  = (const int*)d_in[1];
    const int*   lens  = (const int*)d_in[2];
    const float* emb   = (const float*)d_in[3];
    const float* Wea   = (const float*)d_in[4];
    const float* bea   = (const float*)d_in[5];
    const float* Wda   = (const float*)d_in[6];
    const float* bda   = (const float*)d_in[7];
    const float* wfull = (const float*)d_in[8];
    const float* bfull = (const float*)d_in[9];
    const float* Wih_  = (const float*)d_in[10];
    const float* bih_  = (const float*)d_in[11];
    const float* Wic   = (const float*)d_in[12];
    const float* bic   = (const float*)d_in[13];
    const float* Wfb   = (const float*)d_in[14];
    const float* bfb   = (const float*)d_in[15];
    const float* Wih   = (const float*)d_in[16];
    const float* bih   = (const float*)d_in[17];
    const float* Whh   = (const float*)d_in[18];
    const float* bhh   = (const float*)d_in[19];
    const float* Wfc   = (const float*)d_in[20];
    const float* bfc   = (const float*)d_in[21];
    float* out = (float*)d_out;

    char* w = (char*)d_ws;
    auto carve = [&](size_t bytes) -> void* {
        void* p = (void*)w;
        w += (bytes + 255) & ~(size_t)255;
        return p;
    };
    int* sidx      = (int*)carve(B * 4);
    int* dlen      = (int*)carve(B * 4);
    int* caps_s    = (int*)carve((size_t)B * T * 4);
    float* mean_eo = (float*)carve((size_t)B * ED * 4);
    float* h0      = (float*)carve((size_t)B * DD * 4);
    float* cb0     = (float*)carve((size_t)B * DD * 4);
    float* cb1     = (float*)carve((size_t)B * DD * 4);
    float* att1    = (float*)carve((size_t)B * P * AD * 4);
    float* alphaW  = (float*)carve((size_t)B * P * 4);
    float* xT      = (float*)carve((size_t)KTOT * B * 4);
    float* part    = (float*)carve((size_t)KSPLIT * B * NG * 4);
    float* hseq    = (float*)carve((size_t)TD * B * DD * 4);
    float* embT    = (float*)carve((size_t)TD * E * B * 4);

    k_sort<<<1, 64, 0, stream>>>(lens, caps, sidx, dlen, caps_s, out);
    k_emball<<<dim3(TD, 5), 256, 0, stream>>>(emb, caps_s, embT);
    k_mean<<<dim3(ED / 256, B), 256, 0, stream>>>(eo, sidx, mean_eo);
    k_init<<<(B * DD) / 256, 256, 0, stream>>>(mean_eo, Wih_, bih_, Wic, bic, h0, cb1, xT);
    k_att1<<<dim3((B * P) / 64, AD / 64), 256, 0, stream>>>(eo, Wea, bea, sidx, att1);

    // c(t) lives in cb[t&1]; c(-1)=c0 seeded in cb1 above.
    for (int t = 0; t < TD; t++) {
        const float* cread  = (t & 1) ? cb1 : cb0;   // c(t-2)
        float*       cwrite = (t & 1) ? cb0 : cb1;   // c(t-1)
        kA2f<<<64, 1024, 0, stream>>>(part, bih, bhh, h0, cread, cwrite,
                                      Wda, bda, att1, wfull, bfull, dlen,
                                      alphaW, xT, hseq, out, t);
        const float* hprev = (t == 0) ? h0 : (hseq + (size_t)(t - 1) * B * DD);
        kBf<<<512, 256, 0, stream>>>(eo, sidx, hprev, Wfb, bfb, alphaW, xT);
        kC<<<512, 256, 0, stream>>>(xT, embT + (size_t)t * E * B, Wih, Whh, part);
    }
    // trailing cell: h(TD-1) from part(TD-1); c(TD-2) is in cb[(TD-2)&1] = cb1
    kD<<<(B * DD) / 256, 256, 0, stream>>>(part, bih, bhh,
                                           hseq + (size_t)(TD - 2) * B * DD, cb1, dlen,
                                           hseq + (size_t)(TD - 1) * B * DD, cb0, TD - 1);
    k_predsall<<<dim3(TD, 16), 256, 0, stream>>>(hseq, Wfc, bfc, dlen, out);
}

// Round 5
// 19010.896 us; speedup vs baseline: 1.0150x; 1.0150x over previous
//
#include <hip/hip_runtime.h>
#include <stddef.h>
#include <math.h>

static constexpr int B = 64, P = 196, ED = 2048, AD = 512, DD = 512, E = 300, V = 1000, T = 96, TD = 95;
static constexpr int KX = E + ED;      // 2348
static constexpr int KTOT = KX + DD;   // 2860
static constexpr int KSPLIT = 8;
static constexpr int KPER = 368;       // 23 tiles of 16; 8*368 = 2944 >= 2860
static constexpr int NG = 4 * DD;      // 2048

// d_out layout (all float32): predictions (B,TD,V), caps (B,T), decode_lengths (B),
// alphas (B,TD,P), sort_ind (B)
static constexpr size_t POFF   = 0;
static constexpr size_t CAPOFF = (size_t)B * TD * V;
static constexpr size_t DLOFF  = CAPOFF + (size_t)B * T;
static constexpr size_t AOFF   = DLOFF + B;
static constexpr size_t SOFF   = AOFF + (size_t)B * TD * P;

__device__ __forceinline__ float sigm(float x) { return 1.0f / (1.0f + expf(-x)); }

// ---------------------------------------------------------------------------
// K0: stable descending sort by length + gather caps + zero tail counters
// ---------------------------------------------------------------------------
__global__ __launch_bounds__(64) void k_sort(const int* __restrict__ lens,
                                             const int* __restrict__ caps_in,
                                             int* __restrict__ sidx,
                                             int* __restrict__ dlen,
                                             int* __restrict__ caps_s,
                                             unsigned int* __restrict__ cnt,
                                             float* __restrict__ out) {
    __shared__ int sl[B];
    __shared__ int ss[B];
    int i = threadIdx.x;
    sl[i] = lens[i];
    cnt[i] = 0u;
    __syncthreads();
    int li = sl[i];
    int r = 0;
    for (int j = 0; j < B; j++) {
        int lj = sl[j];
        r += (lj > li) || (lj == li && j < i);
    }
    ss[r] = i;
    sidx[r] = i;
    dlen[r] = li - 1;
    out[DLOFF + r] = (float)(li - 1);
    out[SOFF + r] = (float)i;
    __syncthreads();
    for (int idx = i; idx < B * T; idx += B) {
        int b = idx / T, tt = idx % T;
        int v = caps_in[ss[b] * T + tt];
        caps_s[idx] = v;
        out[CAPOFF + idx] = (float)v;
    }
}

// ---------------------------------------------------------------------------
// kE: precompute ALL timestep embedding gathers: embT[(t*E + k)*B + b]
// ---------------------------------------------------------------------------
__global__ __launch_bounds__(256) void k_emball(const float* __restrict__ emb,
                                                const int* __restrict__ caps_s,
                                                float* __restrict__ embT) {
    int t = blockIdx.x;
    int k0 = blockIdx.y * 60;
    for (int l = threadIdx.x; l < 60 * 64; l += 256) {
        int r = l >> 6, b = l & 63;
        int k = k0 + r;
        int cap = caps_s[b * T + t];
        embT[((size_t)t * E + k) * B + b] = emb[(size_t)cap * E + k];
    }
}

// ---------------------------------------------------------------------------
// K1: mean over P of sorted encoder_out -> mean_eo (B, ED)
// ---------------------------------------------------------------------------
__global__ __launch_bounds__(256) void k_mean(const float* __restrict__ eo,
                                              const int* __restrict__ sidx,
                                              float* __restrict__ mean_eo) {
    int b = blockIdx.y;
    int d = blockIdx.x * 256 + threadIdx.x;
    const float* base = eo + ((size_t)sidx[b] * P) * ED + d;
    float s = 0.f;
    for (int p = 0; p < P; p++) s += base[(size_t)p * ED];
    mean_eo[(size_t)b * ED + d] = s * (1.0f / (float)P);
}

// ---------------------------------------------------------------------------
// K2: h0/c0 init; c0 -> cb1 (c(-1) parity); h0 -> xT h-slot 1 (h(-1) parity)
// ---------------------------------------------------------------------------
__global__ __launch_bounds__(256) void k_init(const float* __restrict__ mean_eo,
                                              const float* __restrict__ Wh, const float* __restrict__ bh,
                                              const float* __restrict__ Wc, const float* __restrict__ bc,
                                              float* __restrict__ h0, float* __restrict__ c0,
                                              float* __restrict__ xT) {
    int idx = blockIdx.x * 256 + threadIdx.x;  // B*DD
    int b = idx >> 9, j = idx & 511;
    const float* m = mean_eo + (size_t)b * ED;
    float ah = bh[j], ac = bc[j];
    for (int k = 0; k < ED; k++) {
        float mv = m[k];
        ah += mv * Wh[(size_t)k * DD + j];
        ac += mv * Wc[(size_t)k * DD + j];
    }
    h0[idx] = ah;
    c0[idx] = ac;
    xT[(size_t)(KX + DD + j) * B + b] = ah;  // slot 1 = parity of t-1 for t=0
}

// ---------------------------------------------------------------------------
// K3: att1[m,n] = eo_sorted[m,:] @ W_enc_att[:,n] + b   (row-major, B*P x AD)
// ---------------------------------------------------------------------------
__global__ __launch_bounds__(256) void k_att1(const float* __restrict__ eo,
                                              const float* __restrict__ W,
                                              const float* __restrict__ bias,
                                              const int* __restrict__ sidx,
                                              float* __restrict__ att1) {
    int m0 = blockIdx.x * 64, n0 = blockIdx.y * 64;
    __shared__ float sA[16][68];
    __shared__ float sB[16][68];
    int tid = threadIdx.x;
    int tx = tid & 15, ty = tid >> 4;
    float acc[4][4] = {};

    int la_m = tid >> 2;
    int la_k = (tid & 3) * 4;
    int lb_k = tid >> 4;
    int lb_n = (tid & 15) * 4;

    int mA = m0 + la_m;
    int bA = mA / P, pA = mA % P;
    const float* arow = eo + ((size_t)sidx[bA] * P + pA) * ED;

    for (int k0 = 0; k0 < ED; k0 += 16) {
        float4 av = *(const float4*)(arow + k0 + la_k);
        sA[la_k + 0][la_m] = av.x;
        sA[la_k + 1][la_m] = av.y;
        sA[la_k + 2][la_m] = av.z;
        sA[la_k + 3][la_m] = av.w;
        float4 bv = *(const float4*)(W + (size_t)(k0 + lb_k) * AD + n0 + lb_n);
        *(float4*)&sB[lb_k][lb_n] = bv;
        __syncthreads();
#pragma unroll
        for (int kk = 0; kk < 16; kk++) {
            float4 a4 = *(const float4*)&sA[kk][ty * 4];
            float4 b4 = *(const float4*)&sB[kk][tx * 4];
            float av_[4] = {a4.x, a4.y, a4.z, a4.w};
            float bv_[4] = {b4.x, b4.y, b4.z, b4.w};
#pragma unroll
            for (int i = 0; i < 4; i++)
#pragma unroll
                for (int j = 0; j < 4; j++) acc[i][j] += av_[i] * bv_[j];
        }
        __syncthreads();
    }
#pragma unroll
    for (int i = 0; i < 4; i++) {
        int m = m0 + ty * 4 + i;
        int n = n0 + tx * 4;
        float4 o;
        o.x = acc[i][0] + bias[n + 0];
        o.y = acc[i][1] + bias[n + 1];
        o.z = acc[i][2] + bias[n + 2];
        o.w = acc[i][3] + bias[n + 3];
        *(float4*)(att1 + (size_t)m * AD + n) = o;
    }
}

// ---------------------------------------------------------------------------
// kA1w: 160 blocks x 256: 16-col tiles, weights read once.
//   blocks [0,32):   att2 cols; blocks [32,160): fg cols (sigm applied)
// ---------------------------------------------------------------------------
__global__ __launch_bounds__(256) void kA1w(const float* __restrict__ hprev,
                                            const float* __restrict__ Wda, const float* __restrict__ bda,
                                            const float* __restrict__ Wfb, const float* __restrict__ bfb,
                                            float* __restrict__ att2g,
                                            float* __restrict__ fg) {
    int bx = blockIdx.x;
    int tid = threadIdx.x;
    bool is_att = (bx < 32);
    int n0 = is_att ? bx * 16 : (bx - 32) * 16;
    __shared__ float sH[16][68];
    __shared__ float sW[16][20];
    float acc[4] = {};
    int tb = tid & 15, tn = tid >> 4;

    for (int k0 = 0; k0 < DD; k0 += 16) {
        {
            int b = tid >> 2, q = tid & 3;
            float4 hv = *(const float4*)(hprev + (size_t)b * DD + k0 + q * 4);
            sH[q * 4 + 0][b] = hv.x;
            sH[q * 4 + 1][b] = hv.y;
            sH[q * 4 + 2][b] = hv.z;
            sH[q * 4 + 3][b] = hv.w;
        }
        if (tid < 64) {
            int kk = tid >> 2, nn = (tid & 3) * 4;
            float4 wv;
            if (is_att) wv = *(const float4*)(Wda + (size_t)(k0 + kk) * AD + n0 + nn);
            else        wv = *(const float4*)(Wfb + (size_t)(k0 + kk) * ED + n0 + nn);
            *(float4*)&sW[kk][nn] = wv;
        }
        __syncthreads();
#pragma unroll
        for (int kk = 0; kk < 16; kk++) {
            float4 hv = *(const float4*)&sH[kk][tb * 4];
            float wv = sW[kk][tn];
            acc[0] += hv.x * wv;
            acc[1] += hv.y * wv;
            acc[2] += hv.z * wv;
            acc[3] += hv.w * wv;
        }
        __syncthreads();
    }
    int n = n0 + tn;
#pragma unroll
    for (int i = 0; i < 4; i++) {
        int b = tb * 4 + i;
        if (is_att) att2g[(size_t)b * AD + n] = acc[i] + bda[n];
        else        fg[(size_t)b * ED + n] = sigm(acc[i] + bfb[n]);
    }
}

// ---------------------------------------------------------------------------
// kA2B: fused softmax + awe. 256 blocks x 1024: b = bid>>2, ch = bid&3.
//   4-way replicated softmax (att1 re-read), then awe over the ch quarter
//   of d (512 d's), xg = fg*awe -> xT rows [E+ch*512 ...).
// ---------------------------------------------------------------------------
__global__ __launch_bounds__(1024) void kA2B(const float* __restrict__ att2g,
                                             const float* __restrict__ att1,
                                             const float* __restrict__ wf,
                                             const float* __restrict__ bfv,
                                             const int* __restrict__ dlen,
                                             const float* __restrict__ eo,
                                             const int* __restrict__ sidx,
                                             const float* __restrict__ fg,
                                             float* __restrict__ xT,
                                             float* __restrict__ out, int t) {
    int bid = blockIdx.x;
    int b = bid >> 2, ch = bid & 3;
    int tid = threadIdx.x;
    __shared__ float sa2[AD];
    __shared__ float swf[AD];
    __shared__ float se[P];
    __shared__ float red[1024];
    __shared__ float partl[8][512];

    if (tid < 512) sa2[tid] = att2g[(size_t)b * AD + tid];
    else           swf[tid - 512] = wf[tid - 512];
    __syncthreads();

    int w = tid >> 6, lane = tid & 63;
    float bf0 = bfv[0];
    for (int p = w; p < P; p += 16) {
        const float* row = att1 + ((size_t)b * P + p) * AD + lane * 8;
        float4 u0 = *(const float4*)row;
        float4 u1 = *(const float4*)(row + 4);
        float4 s0 = *(const float4*)&sa2[lane * 8];
        float4 s1 = *(const float4*)&sa2[lane * 8 + 4];
        float4 w0 = *(const float4*)&swf[lane * 8];
        float4 w1 = *(const float4*)&swf[lane * 8 + 4];
        float acc = fmaxf(u0.x + s0.x, 0.f) * w0.x + fmaxf(u0.y + s0.y, 0.f) * w0.y +
                    fmaxf(u0.z + s0.z, 0.f) * w0.z + fmaxf(u0.w + s0.w, 0.f) * w0.w +
                    fmaxf(u1.x + s1.x, 0.f) * w1.x + fmaxf(u1.y + s1.y, 0.f) * w1.y +
                    fmaxf(u1.z + s1.z, 0.f) * w1.z + fmaxf(u1.w + s1.w, 0.f) * w1.w;
#pragma unroll
        for (int mm = 32; mm >= 1; mm >>= 1) acc += __shfl_xor(acc, mm, 64);
        if (lane == 0) se[p] = acc + bf0;
    }
    __syncthreads();

    red[tid] = (tid < P) ? se[tid] : -1e30f;
    __syncthreads();
    for (int s = 512; s > 0; s >>= 1) {
        if (tid < s) red[tid] = fmaxf(red[tid], red[tid + s]);
        __syncthreads();
    }
    float mx = red[0];
    __syncthreads();
    float ex = (tid < P) ? expf(se[tid] - mx) : 0.f;
    red[tid] = ex;
    __syncthreads();
    for (int s = 512; s > 0; s >>= 1) {
        if (tid < s) red[tid] += red[tid + s];
        __syncthreads();
    }
    float inv = 1.0f / red[0];
    __syncthreads();
    if (tid < P) {
        float a = ex * inv;
        se[tid] = a;  // alpha now lives in se
        if (ch == 0) {
            float m = (dlen[b] > t) ? 1.f : 0.f;
            out[AOFF + ((size_t)b * TD + t) * P + tid] = a * m;
        }
    }
    __syncthreads();

    // awe over the ch quarter: 8 p-groups x 128 d-quads
    int pg = tid >> 7, q = tid & 127;
    int d = ch * 512 + q * 4;
    const float* base = eo + ((size_t)sidx[b] * P) * ED + d;
    float ax = 0.f, ay = 0.f, az = 0.f, aw = 0.f;
    for (int p = pg; p < P; p += 8) {
        float4 v = *(const float4*)(base + (size_t)p * ED);
        float a = se[p];
        ax += v.x * a; ay += v.y * a; az += v.z * a; aw += v.w * a;
    }
    partl[pg][q * 4 + 0] = ax;
    partl[pg][q * 4 + 1] = ay;
    partl[pg][q * 4 + 2] = az;
    partl[pg][q * 4 + 3] = aw;
    __syncthreads();
    if (tid < 512) {
        float s = partl[0][tid] + partl[1][tid] + partl[2][tid] + partl[3][tid] +
                  partl[4][tid] + partl[5][tid] + partl[6][tid] + partl[7][tid];
        int d2 = ch * 512 + tid;
        xT[(size_t)(E + d2) * B + b] = fg[(size_t)b * ED + d2] * s;
    }
}

// ---------------------------------------------------------------------------
// kCD: gates GEMM + fused LSTM cell tail. grid 512 = 8 K-splits x 64 groups.
//   Group nb owns cols {g*512 + nb*8 + jj : g in 0..3, jj in 0..7} -> complete
//   gates for 8 j's. Last-arrival block (agent-scope counter) computes the
//   cell for its 8 j's x 64 b, writes hseq[t], c(t), and xT h-slot[t&1].
// ---------------------------------------------------------------------------
__global__ __launch_bounds__(256) void kCD(const float* __restrict__ xT,
                                           const float* __restrict__ embT_t,
                                           const float* __restrict__ xh_r,
                                           const float* __restrict__ Wih,
                                           const float* __restrict__ Whh,
                                           float* __restrict__ part,
                                           unsigned int* __restrict__ cnt,
                                           const float* __restrict__ bih,
                                           const float* __restrict__ bhh,
                                           const float* __restrict__ h0,
                                           float* __restrict__ hseq,
                                           const float* __restrict__ cread,
                                           float* __restrict__ cwrite,
                                           const int* __restrict__ dlen,
                                           float* __restrict__ xh_w, int t) {
    int bx = blockIdx.x;
    int ks = bx >> 6, nb = bx & 63;
    int tid = threadIdx.x;
    int tb = tid & 15, tn = tid >> 4;
    __shared__ float sW[16][36];
    __shared__ unsigned int sOld;
    float acc[4][2] = {};
    int kbase = ks * KPER;

    for (int tile = 0; tile < 23; tile++) {
        int k0 = kbase + tile * 16;
        if (tid < 128) {
            int kk = tid >> 3, seg = tid & 7;
            int g = seg >> 1, half = seg & 1;
            int kg = k0 + kk;
            int col = g * 512 + nb * 8 + half * 4;
            float4 wv = make_float4(0.f, 0.f, 0.f, 0.f);
            if (kg < KX) wv = *(const float4*)&Wih[(size_t)kg * NG + col];
            else if (kg < KTOT) wv = *(const float4*)&Whh[(size_t)(kg - KX) * NG + col];
            *(float4*)&sW[kk][seg * 4] = wv;
        }
        __syncthreads();
#pragma unroll
        for (int kk = 0; kk < 16; kk++) {
            int kg = k0 + kk;
            float4 xv = make_float4(0.f, 0.f, 0.f, 0.f);
            if (kg < E) xv = *(const float4*)&embT_t[(size_t)kg * B + tb * 4];
            else if (kg < KX) xv = *(const float4*)&xT[(size_t)kg * B + tb * 4];
            else if (kg < KTOT) xv = *(const float4*)&xh_r[(size_t)(kg - KX) * B + tb * 4];
            float w0 = sW[kk][tn * 2 + 0];
            float w1 = sW[kk][tn * 2 + 1];
            acc[0][0] += xv.x * w0; acc[0][1] += xv.x * w1;
            acc[1][0] += xv.y * w0; acc[1][1] += xv.y * w1;
            acc[2][0] += xv.z * w0; acc[2][1] += xv.z * w1;
            acc[3][0] += xv.w * w0; acc[3][1] += xv.w * w1;
        }
        __syncthreads();
    }
    // agent-scope partial stores (visible cross-XCD at MALL)
#pragma unroll
    for (int i = 0; i < 4; i++)
#pragma unroll
        for (int j = 0; j < 2; j++) {
            int b = tb * 4 + i, lc = tn * 2 + j;
            __hip_atomic_store(&part[((size_t)ks * B + b) * NG + nb * 32 + lc], acc[i][j],
                               __ATOMIC_RELAXED, __HIP_MEMORY_SCOPE_AGENT);
        }
    __syncthreads();  // drains vmcnt: all stores of this block complete
    if (tid == 0)
        sOld = __hip_atomic_fetch_add(&cnt[nb], 1u, __ATOMIC_ACQ_REL, __HIP_MEMORY_SCOPE_AGENT);
    __syncthreads();
    if (sOld != 7u) return;

    // --- tail: this block is the 8th arrival; all partials are visible ---
    if (tid == 0)
        __hip_atomic_store(&cnt[nb], 0u, __ATOMIC_RELAXED, __HIP_MEMORY_SCOPE_AGENT);

    const float* holds = (t == 0) ? h0 : (hseq + (size_t)(t - 1) * B * DD);
#pragma unroll
    for (int rep = 0; rep < 2; rep++) {
        int idx = rep * 256 + tid;
        int bb = idx & 63, jj = idx >> 6;
        int j = nb * 8 + jj;
        float g4[4];
#pragma unroll
        for (int g = 0; g < 4; g++) {
            float gv = bih[g * DD + j] + bhh[g * DD + j];
#pragma unroll
            for (int s = 0; s < KSPLIT; s++)
                gv += __hip_atomic_load(&part[((size_t)s * B + bb) * NG + nb * 32 + g * 8 + jj],
                                        __ATOMIC_RELAXED, __HIP_MEMORY_SCOPE_AGENT);
            g4[g] = gv;
        }
        float cold = cread[(size_t)bb * DD + j];
        float hold = holds[(size_t)bb * DD + j];
        float cnew = sigm(g4[1]) * cold + sigm(g4[0]) * tanhf(g4[2]);
        float hnew = sigm(g4[3]) * tanhf(cnew);
        bool m = dlen[bb] > t;
        float h2 = m ? hnew : hold;
        float c2 = m ? cnew : cold;
        hseq[(size_t)t * B * DD + (size_t)bb * DD + j] = h2;
        cwrite[(size_t)bb * DD + j] = c2;
        xh_w[(size_t)j * B + bb] = h2;
    }
}

// ---------------------------------------------------------------------------
// K4: batched preds GEMM: out[b,t,v] = mask * (hseq[t,b,:]@Wfc + bfc)
// ---------------------------------------------------------------------------
__global__ __launch_bounds__(256) void k_predsall(const float* __restrict__ hseq,
                                                  const float* __restrict__ Wfc,
                                                  const float* __restrict__ bfc,
                                                  const int* __restrict__ dlen,
                                                  float* __restrict__ out) {
    int t = blockIdx.x;
    int n0 = blockIdx.y * 64;
    int tid = threadIdx.x;
    int tx = tid & 15, ty = tid >> 4;
    __shared__ float sA[16][68];
    __shared__ float sB[16][68];
    float acc[4][4] = {};
    const float* A = hseq + (size_t)t * B * DD;

    for (int k0 = 0; k0 < DD; k0 += 16) {
        {
            int b = tid >> 2, q = tid & 3;
            float4 hv = *(const float4*)(A + (size_t)b * DD + k0 + q * 4);
            sA[q * 4 + 0][b] = hv.x;
            sA[q * 4 + 1][b] = hv.y;
            sA[q * 4 + 2][b] = hv.z;
            sA[q * 4 + 3][b] = hv.w;
        }
        {
            int kk = tid >> 4, nn = (tid & 15) * 4;
            int c = n0 + nn;
            const float* wrow = Wfc + (size_t)(k0 + kk) * V;
            float4 wv;
            if (c + 3 < V) wv = *(const float4*)(wrow + c);
            else {
                wv.x = (c + 0 < V) ? wrow[c + 0] : 0.f;
                wv.y = (c + 1 < V) ? wrow[c + 1] : 0.f;
                wv.z = (c + 2 < V) ? wrow[c + 2] : 0.f;
                wv.w = (c + 3 < V) ? wrow[c + 3] : 0.f;
            }
            *(float4*)&sB[kk][nn] = wv;
        }
        __syncthreads();
#pragma unroll
        for (int kk = 0; kk < 16; kk++) {
            float4 a4 = *(const float4*)&sA[kk][ty * 4];
            float4 b4 = *(const float4*)&sB[kk][tx * 4];
            float av_[4] = {a4.x, a4.y, a4.z, a4.w};
            float bv_[4] = {b4.x, b4.y, b4.z, b4.w};
#pragma unroll
            for (int i = 0; i < 4; i++)
#pragma unroll
                for (int j = 0; j < 4; j++) acc[i][j] += av_[i] * bv_[j];
        }
        __syncthreads();
    }
#pragma unroll
    for (int i = 0; i < 4; i++) {
        int b = ty * 4 + i;
        bool m = dlen[b] > t;
#pragma unroll
        for (int j = 0; j < 4; j++) {
            int n = n0 + tx * 4 + j;
            if (n < V)
                out[POFF + ((size_t)b * TD + t) * V + n] = m ? (acc[i][j] + bfc[n]) : 0.f;
        }
    }
}

// ---------------------------------------------------------------------------
extern "C" void kernel_launch(void* const* d_in, const int* in_sizes, int n_in,
                              void* d_out, int out_size, void* d_ws, size_t ws_size,
                              hipStream_t stream) {
    const float* eo    = (const float*)d_in[0];
    const int*   caps  = (const int*)d_in[1];
    const int*   lens  = (const int*)d_in[2];
    const float* emb   = (const float*)d_in[3];
    const float* Wea   = (const float*)d_in[4];
    const float* bea   = (const float*)d_in[5];
    const float* Wda   = (const float*)d_in[6];
    const float* bda   = (const float*)d_in[7];
    const float* wfull = (const float*)d_in[8];
    const float* bfull = (const float*)d_in[9];
    const float* Wih_  = (const float*)d_in[10];
    const float* bih_  = (const float*)d_in[11];
    const float* Wic   = (const float*)d_in[12];
    const float* bic   = (const float*)d_in[13];
    const float* Wfb   = (const float*)d_in[14];
    const float* bfb   = (const float*)d_in[15];
    const float* Wih   = (const float*)d_in[16];
    const float* bih   = (const float*)d_in[17];
    const float* Whh   = (const float*)d_in[18];
    const float* bhh   = (const float*)d_in[19];
    const float* Wfc   = (const float*)d_in[20];
    const float* bfc   = (const float*)d_in[21];
    float* out = (float*)d_out;

    char* w = (char*)d_ws;
    auto carve = [&](size_t bytes) -> void* {
        void* p = (void*)w;
        w += (bytes + 255) & ~(size_t)255;
        return p;
    };
    int* sidx      = (int*)carve(B * 4);
    int* dlen      = (int*)carve(B * 4);
    int* caps_s    = (int*)carve((size_t)B * T * 4);
    unsigned int* cnt = (unsigned int*)carve(64 * 4);
    float* mean_eo = (float*)carve((size_t)B * ED * 4);
    float* h0      = (float*)carve((size_t)B * DD * 4);
    float* cb0     = (float*)carve((size_t)B * DD * 4);
    float* cb1     = (float*)carve((size_t)B * DD * 4);
    float* att1    = (float*)carve((size_t)B * P * AD * 4);
    float* att2g   = (float*)carve((size_t)B * AD * 4);
    float* fg      = (float*)carve((size_t)B * ED * 4);
    float* xT      = (float*)carve((size_t)(KTOT + DD) * B * 4);  // + extra h slot
    float* part    = (float*)carve((size_t)KSPLIT * B * NG * 4);
    float* hseq    = (float*)carve((size_t)TD * B * DD * 4);
    float* embT    = (float*)carve((size_t)TD * E * B * 4);
    float* cb[2] = {cb0, cb1};

    k_sort<<<1, 64, 0, stream>>>(lens, caps, sidx, dlen, caps_s, cnt, out);
    k_emball<<<dim3(TD, 5), 256, 0, stream>>>(emb, caps_s, embT);
    k_mean<<<dim3(ED / 256, B), 256, 0, stream>>>(eo, sidx, mean_eo);
    k_init<<<(B * DD) / 256, 256, 0, stream>>>(mean_eo, Wih_, bih_, Wic, bic, h0, cb1, xT);
    k_att1<<<dim3((B * P) / 64, AD / 64), 256, 0, stream>>>(eo, Wea, bea, sidx, att1);

    // h(t) -> xT h-slot[t&1]; h(-1)=h0 seeded in slot 1. c(t) -> cb[t&1]; c(-1)=c0 in cb1.
    for (int t = 0; t < TD; t++) {
        const float* hprev = (t == 0) ? h0 : (hseq + (size_t)(t - 1) * B * DD);
        kA1w<<<160, 256, 0, stream>>>(hprev, Wda, bda, Wfb, bfb, att2g, fg);
        kA2B<<<256, 1024, 0, stream>>>(att2g, att1, wfull, bfull, dlen, eo, sidx, fg, xT, out, t);
        const float* xh_r = xT + (size_t)(KX + ((t + 1) & 1) * DD) * B;
        float*       xh_w = xT + (size_t)(KX + (t & 1) * DD) * B;
        kCD<<<512, 256, 0, stream>>>(xT, embT + (size_t)t * E * B, xh_r, Wih, Whh, part, cnt,
                                     bih, bhh, h0, hseq, cb[(t + 1) & 1], cb[t & 1], dlen, xh_w, t);
    }
    k_predsall<<<dim3(TD, 16), 256, 0, stream>>>(hseq, Wfc, bfc, dlen, out);
}

// Round 6
// 17272.624 us; speedup vs baseline: 1.1171x; 1.1006x over previous
//
#include <hip/hip_runtime.h>
#include <stddef.h>
#include <math.h>

static constexpr int B = 64, P = 196, ED = 2048, AD = 512, DD = 512, E = 300, V = 1000, T = 96, TD = 95;
static constexpr int KX = E + ED;      // 2348
static constexpr int KTOT = KX + DD;   // 2860
static constexpr int KSPLIT = 8;
static constexpr int KPER = 368;       // 23 tiles of 16; 8*368 = 2944 >= 2860
static constexpr int NG = 4 * DD;      // 2048

// d_out layout (all float32): predictions (B,TD,V), caps (B,T), decode_lengths (B),
// alphas (B,TD,P), sort_ind (B)
static constexpr size_t POFF   = 0;
static constexpr size_t CAPOFF = (size_t)B * TD * V;
static constexpr size_t DLOFF  = CAPOFF + (size_t)B * T;
static constexpr size_t AOFF   = DLOFF + B;
static constexpr size_t SOFF   = AOFF + (size_t)B * TD * P;

__device__ __forceinline__ float sigm(float x) { return 1.0f / (1.0f + expf(-x)); }

// ---------------------------------------------------------------------------
// K0: stable descending sort by length + gather caps + zero tail counters
// ---------------------------------------------------------------------------
__global__ __launch_bounds__(64) void k_sort(const int* __restrict__ lens,
                                             const int* __restrict__ caps_in,
                                             int* __restrict__ sidx,
                                             int* __restrict__ dlen,
                                             int* __restrict__ caps_s,
                                             unsigned int* __restrict__ cnt,
                                             float* __restrict__ out) {
    __shared__ int sl[B];
    __shared__ int ss[B];
    int i = threadIdx.x;
    sl[i] = lens[i];
    cnt[i] = 0u;
    __syncthreads();
    int li = sl[i];
    int r = 0;
    for (int j = 0; j < B; j++) {
        int lj = sl[j];
        r += (lj > li) || (lj == li && j < i);
    }
    ss[r] = i;
    sidx[r] = i;
    dlen[r] = li - 1;
    out[DLOFF + r] = (float)(li - 1);
    out[SOFF + r] = (float)i;
    __syncthreads();
    for (int idx = i; idx < B * T; idx += B) {
        int b = idx / T, tt = idx % T;
        int v = caps_in[ss[b] * T + tt];
        caps_s[idx] = v;
        out[CAPOFF + idx] = (float)v;
    }
}

// ---------------------------------------------------------------------------
// kE: precompute ALL timestep embedding gathers: embT[(t*E + k)*B + b]
// ---------------------------------------------------------------------------
__global__ __launch_bounds__(256) void k_emball(const float* __restrict__ emb,
                                                const int* __restrict__ caps_s,
                                                float* __restrict__ embT) {
    int t = blockIdx.x;
    int k0 = blockIdx.y * 60;
    for (int l = threadIdx.x; l < 60 * 64; l += 256) {
        int r = l >> 6, b = l & 63;
        int k = k0 + r;
        int cap = caps_s[b * T + t];
        embT[((size_t)t * E + k) * B + b] = emb[(size_t)cap * E + k];
    }
}

// ---------------------------------------------------------------------------
// K1: mean over P of sorted encoder_out -> mean_eo (B, ED)
// ---------------------------------------------------------------------------
__global__ __launch_bounds__(256) void k_mean(const float* __restrict__ eo,
                                              const int* __restrict__ sidx,
                                              float* __restrict__ mean_eo) {
    int b = blockIdx.y;
    int d = blockIdx.x * 256 + threadIdx.x;
    const float* base = eo + ((size_t)sidx[b] * P) * ED + d;
    float s = 0.f;
    for (int p = 0; p < P; p++) s += base[(size_t)p * ED];
    mean_eo[(size_t)b * ED + d] = s * (1.0f / (float)P);
}

// ---------------------------------------------------------------------------
// K2: h0/c0 init; c0 -> cb1 (c(-1) parity); h0 -> xT h-slot 1 (h(-1) parity)
// ---------------------------------------------------------------------------
__global__ __launch_bounds__(256) void k_init(const float* __restrict__ mean_eo,
                                              const float* __restrict__ Wh, const float* __restrict__ bh,
                                              const float* __restrict__ Wc, const float* __restrict__ bc,
                                              float* __restrict__ h0, float* __restrict__ c0,
                                              float* __restrict__ xT) {
    int idx = blockIdx.x * 256 + threadIdx.x;  // B*DD
    int b = idx >> 9, j = idx & 511;
    const float* m = mean_eo + (size_t)b * ED;
    float ah = bh[j], ac = bc[j];
    for (int k = 0; k < ED; k++) {
        float mv = m[k];
        ah += mv * Wh[(size_t)k * DD + j];
        ac += mv * Wc[(size_t)k * DD + j];
    }
    h0[idx] = ah;
    c0[idx] = ac;
    xT[(size_t)(KX + DD + j) * B + b] = ah;  // slot 1 = parity of h(t-1) for t=0
}

// ---------------------------------------------------------------------------
// K3: att1[m,n] = eo_sorted[m,:] @ W_enc_att[:,n] + b   (row-major, B*P x AD)
// ---------------------------------------------------------------------------
__global__ __launch_bounds__(256) void k_att1(const float* __restrict__ eo,
                                              const float* __restrict__ W,
                                              const float* __restrict__ bias,
                                              const int* __restrict__ sidx,
                                              float* __restrict__ att1) {
    int m0 = blockIdx.x * 64, n0 = blockIdx.y * 64;
    __shared__ float sA[16][68];
    __shared__ float sB[16][68];
    int tid = threadIdx.x;
    int tx = tid & 15, ty = tid >> 4;
    float acc[4][4] = {};

    int la_m = tid >> 2;
    int la_k = (tid & 3) * 4;
    int lb_k = tid >> 4;
    int lb_n = (tid & 15) * 4;

    int mA = m0 + la_m;
    int bA = mA / P, pA = mA % P;
    const float* arow = eo + ((size_t)sidx[bA] * P + pA) * ED;

    for (int k0 = 0; k0 < ED; k0 += 16) {
        float4 av = *(const float4*)(arow + k0 + la_k);
        sA[la_k + 0][la_m] = av.x;
        sA[la_k + 1][la_m] = av.y;
        sA[la_k + 2][la_m] = av.z;
        sA[la_k + 3][la_m] = av.w;
        float4 bv = *(const float4*)(W + (size_t)(k0 + lb_k) * AD + n0 + lb_n);
        *(float4*)&sB[lb_k][lb_n] = bv;
        __syncthreads();
#pragma unroll
        for (int kk = 0; kk < 16; kk++) {
            float4 a4 = *(const float4*)&sA[kk][ty * 4];
            float4 b4 = *(const float4*)&sB[kk][tx * 4];
            float av_[4] = {a4.x, a4.y, a4.z, a4.w};
            float bv_[4] = {b4.x, b4.y, b4.z, b4.w};
#pragma unroll
            for (int i = 0; i < 4; i++)
#pragma unroll
                for (int j = 0; j < 4; j++) acc[i][j] += av_[i] * bv_[j];
        }
        __syncthreads();
    }
#pragma unroll
    for (int i = 0; i < 4; i++) {
        int m = m0 + ty * 4 + i;
        int n = n0 + tx * 4;
        float4 o;
        o.x = acc[i][0] + bias[n + 0];
        o.y = acc[i][1] + bias[n + 1];
        o.z = acc[i][2] + bias[n + 2];
        o.w = acc[i][3] + bias[n + 3];
        *(float4*)(att1 + (size_t)m * AD + n) = o;
    }
}

// ---------------------------------------------------------------------------
// kA1: 80 blocks of 32-col tiles (weights read once), double-buffered LDS +
//      register prefetch, ONE barrier per k-tile.
//   n in [0,512):   att2[b][n]  = hprev@Wda + bda
//   n in [512,2560): fg[b][n-512] = sigm(hprev@Wfb + bfb)
// ---------------------------------------------------------------------------
__global__ __launch_bounds__(256) void kA1(const float* __restrict__ hprev,
                                           const float* __restrict__ Wda, const float* __restrict__ bda,
                                           const float* __restrict__ Wfb, const float* __restrict__ bfb,
                                           float* __restrict__ att2g,
                                           float* __restrict__ fg) {
    int bx = blockIdx.x;
    int tid = threadIdx.x;
    int n0 = bx * 32;
    bool is_att = (n0 < AD);
    const float* W = is_att ? Wda : Wfb;
    int ld = is_att ? AD : ED;
    int colb = is_att ? n0 : n0 - AD;
    __shared__ float sH[2][16][68];
    __shared__ float sW[2][16][36];
    float acc[4][2] = {};
    int tb = tid & 15, tn = tid >> 4;
    int hb = tid >> 2, hq = tid & 3;
    int wk = tid >> 3, wn = (tid & 7) * 4;

    // prologue: tile 0
    float4 hreg = *(const float4*)(hprev + (size_t)hb * DD + hq * 4);
    float4 wreg = make_float4(0.f, 0.f, 0.f, 0.f);
    if (tid < 128) wreg = *(const float4*)(W + (size_t)wk * ld + colb + wn);
    sH[0][hq * 4 + 0][hb] = hreg.x;
    sH[0][hq * 4 + 1][hb] = hreg.y;
    sH[0][hq * 4 + 2][hb] = hreg.z;
    sH[0][hq * 4 + 3][hb] = hreg.w;
    if (tid < 128) *(float4*)&sW[0][wk][wn] = wreg;
    __syncthreads();

    for (int tl = 0; tl < 32; tl++) {
        int cur = tl & 1, nxt = cur ^ 1;
        if (tl < 31) {
            int k0 = (tl + 1) * 16;
            hreg = *(const float4*)(hprev + (size_t)hb * DD + k0 + hq * 4);
            if (tid < 128) wreg = *(const float4*)(W + (size_t)(k0 + wk) * ld + colb + wn);
        }
#pragma unroll
        for (int kk = 0; kk < 16; kk++) {
            float4 hv = *(const float4*)&sH[cur][kk][tb * 4];
            float w0 = sW[cur][kk][tn * 2 + 0];
            float w1 = sW[cur][kk][tn * 2 + 1];
            acc[0][0] += hv.x * w0; acc[0][1] += hv.x * w1;
            acc[1][0] += hv.y * w0; acc[1][1] += hv.y * w1;
            acc[2][0] += hv.z * w0; acc[2][1] += hv.z * w1;
            acc[3][0] += hv.w * w0; acc[3][1] += hv.w * w1;
        }
        if (tl < 31) {
            sH[nxt][hq * 4 + 0][hb] = hreg.x;
            sH[nxt][hq * 4 + 1][hb] = hreg.y;
            sH[nxt][hq * 4 + 2][hb] = hreg.z;
            sH[nxt][hq * 4 + 3][hb] = hreg.w;
            if (tid < 128) *(float4*)&sW[nxt][wk][wn] = wreg;
        }
        __syncthreads();
    }
#pragma unroll
    for (int i = 0; i < 4; i++)
#pragma unroll
        for (int j = 0; j < 2; j++) {
            int b = tb * 4 + i;
            int n = n0 + tn * 2 + j;
            float v = acc[i][j];
            if (is_att) att2g[(size_t)b * AD + n] = v + bda[n];
            else {
                int d = n - AD;
                fg[(size_t)b * ED + d] = sigm(v + bfb[d]);
            }
        }
}

// ---------------------------------------------------------------------------
// kA2: per-b softmax: e = relu(att1+att2)·wf + bf ; alpha (ws) + masked out.
//      1024 threads: 16 waves, one att1 row per wave per iter.
// ---------------------------------------------------------------------------
__global__ __launch_bounds__(1024) void kA2(const float* __restrict__ att2g,
                                            const float* __restrict__ att1,
                                            const float* __restrict__ wf,
                                            const float* __restrict__ bfv,
                                            const int* __restrict__ dlen,
                                            float* __restrict__ alpha,
                                            float* __restrict__ out, int t) {
    int b = blockIdx.x;
    int tid = threadIdx.x;
    __shared__ float sa2[AD];
    __shared__ float swf[AD];
    __shared__ float se[P];
    __shared__ float red[1024];

    if (tid < AD) {
        sa2[tid] = att2g[(size_t)b * AD + tid];
        swf[tid] = wf[tid];
    }
    __syncthreads();

    int w = tid >> 6, lane = tid & 63;
    float bf0 = bfv[0];
#pragma unroll 2
    for (int p = w; p < P; p += 16) {
        const float* row = att1 + ((size_t)b * P + p) * AD + lane * 8;
        float4 u0 = *(const float4*)row;
        float4 u1 = *(const float4*)(row + 4);
        float4 s0 = *(const float4*)&sa2[lane * 8];
        float4 s1 = *(const float4*)&sa2[lane * 8 + 4];
        float4 w0 = *(const float4*)&swf[lane * 8];
        float4 w1 = *(const float4*)&swf[lane * 8 + 4];
        float acc = fmaxf(u0.x + s0.x, 0.f) * w0.x + fmaxf(u0.y + s0.y, 0.f) * w0.y +
                    fmaxf(u0.z + s0.z, 0.f) * w0.z + fmaxf(u0.w + s0.w, 0.f) * w0.w +
                    fmaxf(u1.x + s1.x, 0.f) * w1.x + fmaxf(u1.y + s1.y, 0.f) * w1.y +
                    fmaxf(u1.z + s1.z, 0.f) * w1.z + fmaxf(u1.w + s1.w, 0.f) * w1.w;
#pragma unroll
        for (int m = 32; m >= 1; m >>= 1) acc += __shfl_xor(acc, m, 64);
        if (lane == 0) se[p] = acc + bf0;
    }
    __syncthreads();

    red[tid] = (tid < P) ? se[tid] : -1e30f;
    __syncthreads();
    for (int s = 512; s > 0; s >>= 1) {
        if (tid < s) red[tid] = fmaxf(red[tid], red[tid + s]);
        __syncthreads();
    }
    float mx = red[0];
    __syncthreads();
    float ex = (tid < P) ? expf(se[tid] - mx) : 0.f;
    red[tid] = ex;
    __syncthreads();
    for (int s = 512; s > 0; s >>= 1) {
        if (tid < s) red[tid] += red[tid + s];
        __syncthreads();
    }
    float inv = 1.0f / red[0];
    if (tid < P) {
        float a = ex * inv;
        alpha[(size_t)b * P + tid] = a;
        float m = (dlen[b] > t) ? 1.f : 0.f;
        out[AOFF + ((size_t)b * TD + t) * P + tid] = a * m;
    }
}

// ---------------------------------------------------------------------------
// kB: awe + xg = fg*awe, write K-major xT rows [300, 2348).
//     float4 along d, p split 4-ways across waves, LDS reduce. grid (8, B).
// ---------------------------------------------------------------------------
__global__ __launch_bounds__(256) void kB(const float* __restrict__ eo,
                                          const int* __restrict__ sidx,
                                          const float* __restrict__ alpha,
                                          const float* __restrict__ fg,
                                          float* __restrict__ xT) {
    int b = blockIdx.y, ch = blockIdx.x, tid = threadIdx.x;
    int pg = tid >> 6, lane = tid & 63;
    __shared__ float sal[P];
    __shared__ float part[4][260];
    if (tid < P) sal[tid] = alpha[(size_t)b * P + tid];
    __syncthreads();
    int d = ch * 256 + lane * 4;
    const float* base = eo + ((size_t)sidx[b] * P) * ED + d;
    float ax = 0.f, ay = 0.f, az = 0.f, aw = 0.f;
#pragma unroll 7
    for (int i = 0; i < 49; i++) {
        int p = pg + i * 4;
        float4 v = *(const float4*)(base + (size_t)p * ED);
        float a = sal[p];
        ax += v.x * a; ay += v.y * a; az += v.z * a; aw += v.w * a;
    }
    part[pg][lane * 4 + 0] = ax;
    part[pg][lane * 4 + 1] = ay;
    part[pg][lane * 4 + 2] = az;
    part[pg][lane * 4 + 3] = aw;
    __syncthreads();
    if (tid < 64) {
        int d0 = ch * 256 + tid * 4;
        float4 g = *(const float4*)(fg + (size_t)b * ED + d0);
        float s0 = part[0][tid * 4 + 0] + part[1][tid * 4 + 0] + part[2][tid * 4 + 0] + part[3][tid * 4 + 0];
        float s1 = part[0][tid * 4 + 1] + part[1][tid * 4 + 1] + part[2][tid * 4 + 1] + part[3][tid * 4 + 1];
        float s2 = part[0][tid * 4 + 2] + part[1][tid * 4 + 2] + part[2][tid * 4 + 2] + part[3][tid * 4 + 2];
        float s3 = part[0][tid * 4 + 3] + part[1][tid * 4 + 3] + part[2][tid * 4 + 3] + part[3][tid * 4 + 3];
        xT[(size_t)(E + d0 + 0) * B + b] = g.x * s0;
        xT[(size_t)(E + d0 + 1) * B + b] = g.y * s1;
        xT[(size_t)(E + d0 + 2) * B + b] = g.z * s2;
        xT[(size_t)(E + d0 + 3) * B + b] = g.w * s3;
    }
}

// ---------------------------------------------------------------------------
// kCD: gates GEMM (R2 kC layout: contiguous 32-col tiles, weights read once,
//   dbuf LDS + reg prefetch, 1 barrier/tile) + fused last-arrival cell tail.
//   grid 512 = 8 ksplits x 64 n-tiles. Block nb covers cols [nb*32, nb*32+32)
//   = gate g=nb>>4, j-group jg=nb&15. cnt[jg] counts 32 arrivals (8 ks x 4 g);
//   last arrival computes the cell for j in [jg*32, jg*32+32) x 64 b.
// ---------------------------------------------------------------------------
__global__ __launch_bounds__(256) void kCD(const float* __restrict__ xT,
                                           const float* __restrict__ embT_t,
                                           const float* __restrict__ xh_r,
                                           const float* __restrict__ Wih,
                                           const float* __restrict__ Whh,
                                           float* __restrict__ part,
                                           unsigned int* __restrict__ cnt,
                                           const float* __restrict__ bih,
                                           const float* __restrict__ bhh,
                                           const float* __restrict__ h0,
                                           float* __restrict__ hseq,
                                           const float* __restrict__ cread,
                                           float* __restrict__ cwrite,
                                           const int* __restrict__ dlen,
                                           float* __restrict__ xh_w, int t) {
    int bx = blockIdx.x;
    int ks = bx >> 6, nb = bx & 63;
    int n0 = nb * 32;
    int tid = threadIdx.x;
    int tb = tid & 15, tn = tid >> 4;
    int wk = tid >> 3, wn = (tid & 7) * 4;
    __shared__ float sW[2][16][36];
    __shared__ unsigned int sOld;
    float acc[4][2] = {};
    int kbase = ks * KPER;

    auto ldw = [&](int tile) -> float4 {
        int kg = kbase + tile * 16 + wk;
        float4 wv = make_float4(0.f, 0.f, 0.f, 0.f);
        if (kg < KX) wv = *(const float4*)&Wih[(size_t)kg * NG + n0 + wn];
        else if (kg < KTOT) wv = *(const float4*)&Whh[(size_t)(kg - KX) * NG + n0 + wn];
        return wv;
    };

    float4 wreg = make_float4(0.f, 0.f, 0.f, 0.f);
    if (tid < 128) {
        wreg = ldw(0);
        *(float4*)&sW[0][wk][wn] = wreg;
    }
    __syncthreads();

    for (int tile = 0; tile < 23; tile++) {
        int cur = tile & 1, nxt = cur ^ 1;
        if (tile < 22 && tid < 128) wreg = ldw(tile + 1);
#pragma unroll
        for (int kk = 0; kk < 16; kk++) {
            int kg = kbase + tile * 16 + kk;
            float4 xv = make_float4(0.f, 0.f, 0.f, 0.f);
            if (kg < E) xv = *(const float4*)&embT_t[(size_t)kg * B + tb * 4];
            else if (kg < KX) xv = *(const float4*)&xT[(size_t)kg * B + tb * 4];
            else if (kg < KTOT) xv = *(const float4*)&xh_r[(size_t)(kg - KX) * B + tb * 4];
            float w0 = sW[cur][kk][tn * 2 + 0];
            float w1 = sW[cur][kk][tn * 2 + 1];
            acc[0][0] += xv.x * w0; acc[0][1] += xv.x * w1;
            acc[1][0] += xv.y * w0; acc[1][1] += xv.y * w1;
            acc[2][0] += xv.z * w0; acc[2][1] += xv.z * w1;
            acc[3][0] += xv.w * w0; acc[3][1] += xv.w * w1;
        }
        if (tile < 22 && tid < 128) *(float4*)&sW[nxt][wk][wn] = wreg;
        __syncthreads();
    }

    // agent-scope partial stores (R5-proven visibility pattern)
#pragma unroll
    for (int i = 0; i < 4; i++)
#pragma unroll
        for (int j = 0; j < 2; j++) {
            int b = tb * 4 + i, lc = tn * 2 + j;
            __hip_atomic_store(&part[((size_t)ks * B + b) * NG + n0 + lc], acc[i][j],
                               __ATOMIC_RELAXED, __HIP_MEMORY_SCOPE_AGENT);
        }
    __syncthreads();  // drains vmcnt: all this block's stores complete
    int jg = nb & 15;
    if (tid == 0)
        sOld = __hip_atomic_fetch_add(&cnt[jg], 1u, __ATOMIC_ACQ_REL, __HIP_MEMORY_SCOPE_AGENT);
    __syncthreads();
    if (sOld != 31u) return;

    // --- tail: 32nd arrival; all partials for j-group jg are visible ---
    if (tid == 0)
        __hip_atomic_store(&cnt[jg], 0u, __ATOMIC_RELAXED, __HIP_MEMORY_SCOPE_AGENT);

    const float* holds = (t == 0) ? h0 : (hseq + (size_t)(t - 1) * B * DD);
#pragma unroll
    for (int rep = 0; rep < 8; rep++) {
        int idx = rep * 256 + tid;   // 0..2047
        int bb = idx >> 5;           // 0..63
        int jj = idx & 31;           // 0..31
        int j = jg * 32 + jj;
        float g4[4];
#pragma unroll
        for (int g = 0; g < 4; g++) {
            float gv = bih[g * DD + j] + bhh[g * DD + j];
#pragma unroll
            for (int s = 0; s < KSPLIT; s++)
                gv += __hip_atomic_load(&part[((size_t)s * B + bb) * NG + g * 512 + j],
                                        __ATOMIC_RELAXED, __HIP_MEMORY_SCOPE_AGENT);
            g4[g] = gv;
        }
        float cold = cread[(size_t)bb * DD + j];
        float hold = holds[(size_t)bb * DD + j];
        float cnew = sigm(g4[1]) * cold + sigm(g4[0]) * tanhf(g4[2]);
        float hnew = sigm(g4[3]) * tanhf(cnew);
        bool m = dlen[bb] > t;
        float h2 = m ? hnew : hold;
        float c2 = m ? cnew : cold;
        hseq[(size_t)t * B * DD + (size_t)bb * DD + j] = h2;
        cwrite[(size_t)bb * DD + j] = c2;
        xh_w[(size_t)j * B + bb] = h2;
    }
}

// ---------------------------------------------------------------------------
// K4: batched preds GEMM: out[b,t,v] = mask * (hseq[t,b,:]@Wfc + bfc)
// ---------------------------------------------------------------------------
__global__ __launch_bounds__(256) void k_predsall(const float* __restrict__ hseq,
                                                  const float* __restrict__ Wfc,
                                                  const float* __restrict__ bfc,
                                                  const int* __restrict__ dlen,
                                                  float* __restrict__ out) {
    int t = blockIdx.x;
    int n0 = blockIdx.y * 64;
    int tid = threadIdx.x;
    int tx = tid & 15, ty = tid >> 4;
    __shared__ float sA[16][68];
    __shared__ float sB[16][68];
    float acc[4][4] = {};
    const float* A = hseq + (size_t)t * B * DD;

    for (int k0 = 0; k0 < DD; k0 += 16) {
        {
            int b = tid >> 2, q = tid & 3;
            float4 hv = *(const float4*)(A + (size_t)b * DD + k0 + q * 4);
            sA[q * 4 + 0][b] = hv.x;
            sA[q * 4 + 1][b] = hv.y;
            sA[q * 4 + 2][b] = hv.z;
            sA[q * 4 + 3][b] = hv.w;
        }
        {
            int kk = tid >> 4, nn = (tid & 15) * 4;
            int c = n0 + nn;
            const float* wrow = Wfc + (size_t)(k0 + kk) * V;
            float4 wv;
            if (c + 3 < V) wv = *(const float4*)(wrow + c);
            else {
                wv.x = (c + 0 < V) ? wrow[c + 0] : 0.f;
                wv.y = (c + 1 < V) ? wrow[c + 1] : 0.f;
                wv.z = (c + 2 < V) ? wrow[c + 2] : 0.f;
                wv.w = (c + 3 < V) ? wrow[c + 3] : 0.f;
            }
            *(float4*)&sB[kk][nn] = wv;
        }
        __syncthreads();
#pragma unroll
        for (int kk = 0; kk < 16; kk++) {
            float4 a4 = *(const float4*)&sA[kk][ty * 4];
            float4 b4 = *(const float4*)&sB[kk][tx * 4];
            float av_[4] = {a4.x, a4.y, a4.z, a4.w};
            float bv_[4] = {b4.x, b4.y, b4.z, b4.w};
#pragma unroll
            for (int i = 0; i < 4; i++)
#pragma unroll
                for (int j = 0; j < 4; j++) acc[i][j] += av_[i] * bv_[j];
        }
        __syncthreads();
    }
#pragma unroll
    for (int i = 0; i < 4; i++) {
        int b = ty * 4 + i;
        bool m = dlen[b] > t;
#pragma unroll
        for (int j = 0; j < 4; j++) {
            int n = n0 + tx * 4 + j;
            if (n < V)
                out[POFF + ((size_t)b * TD + t) * V + n] = m ? (acc[i][j] + bfc[n]) : 0.f;
        }
    }
}

// ---------------------------------------------------------------------------
extern "C" void kernel_launch(void* const* d_in, const int* in_sizes, int n_in,
                              void* d_out, int out_size, void* d_ws, size_t ws_size,
                              hipStream_t stream) {
    const float* eo    = (const float*)d_in[0];
    const int*   caps  = (const int*)d_in[1];
    const int*   lens  = (const int*)d_in[2];
    const float* emb   = (const float*)d_in[3];
    const float* Wea   = (const float*)d_in[4];
    const float* bea   = (const float*)d_in[5];
    const float* Wda   = (const float*)d_in[6];
    const float* bda   = (const float*)d_in[7];
    const float* wfull = (const float*)d_in[8];
    const float* bfull = (const float*)d_in[9];
    const float* Wih_  = (const float*)d_in[10];
    const float* bih_  = (const float*)d_in[11];
    const float* Wic   = (const float*)d_in[12];
    const float* bic   = (const float*)d_in[13];
    const float* Wfb   = (const float*)d_in[14];
    const float* bfb   = (const float*)d_in[15];
    const float* Wih   = (const float*)d_in[16];
    const float* bih   = (const float*)d_in[17];
    const float* Whh   = (const float*)d_in[18];
    const float* bhh   = (const float*)d_in[19];
    const float* Wfc   = (const float*)d_in[20];
    const float* bfc   = (const float*)d_in[21];
    float* out = (float*)d_out;

    char* w = (char*)d_ws;
    auto carve = [&](size_t bytes) -> void* {
        void* p = (void*)w;
        w += (bytes + 255) & ~(size_t)255;
        return p;
    };
    int* sidx      = (int*)carve(B * 4);
    int* dlen      = (int*)carve(B * 4);
    int* caps_s    = (int*)carve((size_t)B * T * 4);
    unsigned int* cnt = (unsigned int*)carve(64 * 4);
    float* mean_eo = (float*)carve((size_t)B * ED * 4);
    float* h0      = (float*)carve((size_t)B * DD * 4);
    float* cb0     = (float*)carve((size_t)B * DD * 4);
    float* cb1     = (float*)carve((size_t)B * DD * 4);
    float* att1    = (float*)carve((size_t)B * P * AD * 4);
    float* alphaW  = (float*)carve((size_t)B * P * 4);
    float* att2g   = (float*)carve((size_t)B * AD * 4);
    float* fg      = (float*)carve((size_t)B * ED * 4);
    float* xT      = (float*)carve((size_t)(KTOT + DD) * B * 4);  // + extra h slot
    float* part    = (float*)carve((size_t)KSPLIT * B * NG * 4);
    float* hseq    = (float*)carve((size_t)TD * B * DD * 4);
    float* embT    = (float*)carve((size_t)TD * E * B * 4);
    float* cb[2] = {cb0, cb1};

    k_sort<<<1, 64, 0, stream>>>(lens, caps, sidx, dlen, caps_s, cnt, out);
    k_emball<<<dim3(TD, 5), 256, 0, stream>>>(emb, caps_s, embT);
    k_mean<<<dim3(ED / 256, B), 256, 0, stream>>>(eo, sidx, mean_eo);
    k_init<<<(B * DD) / 256, 256, 0, stream>>>(mean_eo, Wih_, bih_, Wic, bic, h0, cb1, xT);
    k_att1<<<dim3((B * P) / 64, AD / 64), 256, 0, stream>>>(eo, Wea, bea, sidx, att1);

    // h(t) -> xT h-slot[t&1]; h(-1)=h0 in slot 1. c(t) -> cb[t&1]; c(-1)=c0 in cb1.
    for (int t = 0; t < TD; t++) {
        const float* hprev = (t == 0) ? h0 : (hseq + (size_t)(t - 1) * B * DD);
        kA1<<<80, 256, 0, stream>>>(hprev, Wda, bda, Wfb, bfb, att2g, fg);
        kA2<<<64, 1024, 0, stream>>>(att2g, att1, wfull, bfull, dlen, alphaW, out, t);
        kB<<<dim3(8, B), 256, 0, stream>>>(eo, sidx, alphaW, fg, xT);
        const float* xh_r = xT + (size_t)(KX + ((t + 1) & 1) * DD) * B;
        float*       xh_w = xT + (size_t)(KX + (t & 1) * DD) * B;
        kCD<<<512, 256, 0, stream>>>(xT, embT + (size_t)t * E * B, xh_r, Wih, Whh, part, cnt,
                                     bih, bhh, h0, hseq, cb[(t + 1) & 1], cb[t & 1], dlen, xh_w, t);
    }
    k_predsall<<<dim3(TD, 16), 256, 0, stream>>>(hseq, Wfc, bfc, dlen, out);
}

// Round 7
// 16873.386 us; speedup vs baseline: 1.1436x; 1.0237x over previous
//
#include <hip/hip_runtime.h>
#include <stddef.h>
#include <math.h>

static constexpr int B = 64, P = 196, ED = 2048, AD = 512, DD = 512, E = 300, V = 1000, T = 96, TD = 95;
static constexpr int KX = E + ED;      // 2348
static constexpr int KTOT = KX + DD;   // 2860
static constexpr int KSPLIT = 8;
static constexpr int KPER = 368;       // 23 tiles of 16; 8*368 = 2944 >= 2860
static constexpr int NG = 4 * DD;      // 2048
static constexpr int NC = 2560;        // combined att2(512) + fg(2048) col space

// d_out layout (all float32): predictions (B,TD,V), caps (B,T), decode_lengths (B),
// alphas (B,TD,P), sort_ind (B)
static constexpr size_t POFF   = 0;
static constexpr size_t CAPOFF = (size_t)B * TD * V;
static constexpr size_t DLOFF  = CAPOFF + (size_t)B * T;
static constexpr size_t AOFF   = DLOFF + B;
static constexpr size_t SOFF   = AOFF + (size_t)B * TD * P;

__device__ __forceinline__ float sigm(float x) { return 1.0f / (1.0f + expf(-x)); }

// ---------------------------------------------------------------------------
// K0: stable descending sort by length + gather caps + zero tail counters
// ---------------------------------------------------------------------------
__global__ __launch_bounds__(64) void k_sort(const int* __restrict__ lens,
                                             const int* __restrict__ caps_in,
                                             int* __restrict__ sidx,
                                             int* __restrict__ dlen,
                                             int* __restrict__ caps_s,
                                             unsigned int* __restrict__ cnt,
                                             float* __restrict__ out) {
    __shared__ int sl[B];
    __shared__ int ss[B];
    int i = threadIdx.x;
    sl[i] = lens[i];
    cnt[i] = 0u;
    cnt[i + 64] = 0u;
    __syncthreads();
    int li = sl[i];
    int r = 0;
    for (int j = 0; j < B; j++) {
        int lj = sl[j];
        r += (lj > li) || (lj == li && j < i);
    }
    ss[r] = i;
    sidx[r] = i;
    dlen[r] = li - 1;
    out[DLOFF + r] = (float)(li - 1);
    out[SOFF + r] = (float)i;
    __syncthreads();
    for (int idx = i; idx < B * T; idx += B) {
        int b = idx / T, tt = idx % T;
        int v = caps_in[ss[b] * T + tt];
        caps_s[idx] = v;
        out[CAPOFF + idx] = (float)v;
    }
}

// ---------------------------------------------------------------------------
// kE: precompute ALL timestep embedding gathers: embT[(t*E + k)*B + b]
// ---------------------------------------------------------------------------
__global__ __launch_bounds__(256) void k_emball(const float* __restrict__ emb,
                                                const int* __restrict__ caps_s,
                                                float* __restrict__ embT) {
    int t = blockIdx.x;
    int k0 = blockIdx.y * 60;
    for (int l = threadIdx.x; l < 60 * 64; l += 256) {
        int r = l >> 6, b = l & 63;
        int k = k0 + r;
        int cap = caps_s[b * T + t];
        embT[((size_t)t * E + k) * B + b] = emb[(size_t)cap * E + k];
    }
}

// ---------------------------------------------------------------------------
// K1: mean over P of sorted encoder_out -> mean_eo (B, ED)
// ---------------------------------------------------------------------------
__global__ __launch_bounds__(256) void k_mean(const float* __restrict__ eo,
                                              const int* __restrict__ sidx,
                                              float* __restrict__ mean_eo) {
    int b = blockIdx.y;
    int d = blockIdx.x * 256 + threadIdx.x;
    const float* base = eo + ((size_t)sidx[b] * P) * ED + d;
    float s = 0.f;
    for (int p = 0; p < P; p++) s += base[(size_t)p * ED];
    mean_eo[(size_t)b * ED + d] = s * (1.0f / (float)P);
}

// ---------------------------------------------------------------------------
// K2: h0/c0 init; c0 -> cb1 (c(-1) parity); h0 -> xT h-slot 1 (h(-1) parity)
// ---------------------------------------------------------------------------
__global__ __launch_bounds__(256) void k_init(const float* __restrict__ mean_eo,
                                              const float* __restrict__ Wh, const float* __restrict__ bh,
                                              const float* __restrict__ Wc, const float* __restrict__ bc,
                                              float* __restrict__ h0, float* __restrict__ c0,
                                              float* __restrict__ xT) {
    int idx = blockIdx.x * 256 + threadIdx.x;  // B*DD
    int b = idx >> 9, j = idx & 511;
    const float* m = mean_eo + (size_t)b * ED;
    float ah = bh[j], ac = bc[j];
    for (int k = 0; k < ED; k++) {
        float mv = m[k];
        ah += mv * Wh[(size_t)k * DD + j];
        ac += mv * Wc[(size_t)k * DD + j];
    }
    h0[idx] = ah;
    c0[idx] = ac;
    xT[(size_t)(KX + DD + j) * B + b] = ah;  // slot 1 = parity of h(t-1) for t=0
}

// ---------------------------------------------------------------------------
// K3: att1[m,n] = eo_sorted[m,:] @ W_enc_att[:,n] + b   (row-major, B*P x AD)
// ---------------------------------------------------------------------------
__global__ __launch_bounds__(256) void k_att1(const float* __restrict__ eo,
                                              const float* __restrict__ W,
                                              const float* __restrict__ bias,
                                              const int* __restrict__ sidx,
                                              float* __restrict__ att1) {
    int m0 = blockIdx.x * 64, n0 = blockIdx.y * 64;
    __shared__ float sA[16][68];
    __shared__ float sB[16][68];
    int tid = threadIdx.x;
    int tx = tid & 15, ty = tid >> 4;
    float acc[4][4] = {};

    int la_m = tid >> 2;
    int la_k = (tid & 3) * 4;
    int lb_k = tid >> 4;
    int lb_n = (tid & 15) * 4;

    int mA = m0 + la_m;
    int bA = mA / P, pA = mA % P;
    const float* arow = eo + ((size_t)sidx[bA] * P + pA) * ED;

    for (int k0 = 0; k0 < ED; k0 += 16) {
        float4 av = *(const float4*)(arow + k0 + la_k);
        sA[la_k + 0][la_m] = av.x;
        sA[la_k + 1][la_m] = av.y;
        sA[la_k + 2][la_m] = av.z;
        sA[la_k + 3][la_m] = av.w;
        float4 bv = *(const float4*)(W + (size_t)(k0 + lb_k) * AD + n0 + lb_n);
        *(float4*)&sB[lb_k][lb_n] = bv;
        __syncthreads();
#pragma unroll
        for (int kk = 0; kk < 16; kk++) {
            float4 a4 = *(const float4*)&sA[kk][ty * 4];
            float4 b4 = *(const float4*)&sB[kk][tx * 4];
            float av_[4] = {a4.x, a4.y, a4.z, a4.w};
            float bv_[4] = {b4.x, b4.y, b4.z, b4.w};
#pragma unroll
            for (int i = 0; i < 4; i++)
#pragma unroll
                for (int j = 0; j < 4; j++) acc[i][j] += av_[i] * bv_[j];
        }
        __syncthreads();
    }
#pragma unroll
    for (int i = 0; i < 4; i++) {
        int m = m0 + ty * 4 + i;
        int n = n0 + tx * 4;
        float4 o;
        o.x = acc[i][0] + bias[n + 0];
        o.y = acc[i][1] + bias[n + 1];
        o.z = acc[i][2] + bias[n + 2];
        o.w = acc[i][3] + bias[n + 3];
        *(float4*)(att1 + (size_t)m * AD + n) = o;
    }
}

// ---------------------------------------------------------------------------
// kA1: att2 + fg GEMM, 4-way k-split: grid 320 = 80 n-tiles(32) x 4 ksplits.
//   Each block: 8 k-tiles (dbuf LDS + reg prefetch), partials to part1,
//   last-arrival (cnt1[nb], 4 arrivals) applies bias (+sigm for fg cols).
// ---------------------------------------------------------------------------
__global__ __launch_bounds__(256) void kA1(const float* __restrict__ hprev,
                                           const float* __restrict__ Wda,
                                           const float* __restrict__ Wfb,
                                           const float* __restrict__ bda,
                                           const float* __restrict__ bfb,
                                           float* __restrict__ part1,
                                           unsigned int* __restrict__ cnt1,
                                           float* __restrict__ att2g,
                                           float* __restrict__ fg) {
    int bx = blockIdx.x;
    int nb = bx >> 2, ks = bx & 3;
    int n0 = nb * 32;                  // combined col space [att2 512 | fg 2048]
    bool is_att = (n0 < AD);
    const float* W = is_att ? Wda : Wfb;
    int ld = is_att ? AD : ED;
    int colb = is_att ? n0 : n0 - AD;
    int kbase = ks * 128;              // 8 tiles of 16
    int tid = threadIdx.x;
    __shared__ float sH[2][16][68];
    __shared__ float sW[2][16][36];
    __shared__ unsigned int sOld;
    float acc[4][2] = {};
    int tb = tid & 15, tn = tid >> 4;
    int hb = tid >> 2, hq = tid & 3;
    int wk = tid >> 3, wn = (tid & 7) * 4;

    float4 hreg = *(const float4*)(hprev + (size_t)hb * DD + kbase + hq * 4);
    float4 wreg = make_float4(0.f, 0.f, 0.f, 0.f);
    if (tid < 128) wreg = *(const float4*)(W + (size_t)(kbase + wk) * ld + colb + wn);
    sH[0][hq * 4 + 0][hb] = hreg.x;
    sH[0][hq * 4 + 1][hb] = hreg.y;
    sH[0][hq * 4 + 2][hb] = hreg.z;
    sH[0][hq * 4 + 3][hb] = hreg.w;
    if (tid < 128) *(float4*)&sW[0][wk][wn] = wreg;
    __syncthreads();

    for (int tl = 0; tl < 8; tl++) {
        int cur = tl & 1, nxt = cur ^ 1;
        if (tl < 7) {
            int k0 = kbase + (tl + 1) * 16;
            hreg = *(const float4*)(hprev + (size_t)hb * DD + k0 + hq * 4);
            if (tid < 128) wreg = *(const float4*)(W + (size_t)(k0 + wk) * ld + colb + wn);
        }
#pragma unroll
        for (int kk = 0; kk < 16; kk++) {
            float4 hv = *(const float4*)&sH[cur][kk][tb * 4];
            float w0 = sW[cur][kk][tn * 2 + 0];
            float w1 = sW[cur][kk][tn * 2 + 1];
            acc[0][0] += hv.x * w0; acc[0][1] += hv.x * w1;
            acc[1][0] += hv.y * w0; acc[1][1] += hv.y * w1;
            acc[2][0] += hv.z * w0; acc[2][1] += hv.z * w1;
            acc[3][0] += hv.w * w0; acc[3][1] += hv.w * w1;
        }
        if (tl < 7) {
            sH[nxt][hq * 4 + 0][hb] = hreg.x;
            sH[nxt][hq * 4 + 1][hb] = hreg.y;
            sH[nxt][hq * 4 + 2][hb] = hreg.z;
            sH[nxt][hq * 4 + 3][hb] = hreg.w;
            if (tid < 128) *(float4*)&sW[nxt][wk][wn] = wreg;
        }
        __syncthreads();
    }

    // agent-scope partial stores
#pragma unroll
    for (int i = 0; i < 4; i++)
#pragma unroll
        for (int j = 0; j < 2; j++) {
            int b = tb * 4 + i, n = n0 + tn * 2 + j;
            __hip_atomic_store(&part1[((size_t)ks * B + b) * NC + n], acc[i][j],
                               __ATOMIC_RELAXED, __HIP_MEMORY_SCOPE_AGENT);
        }
    __syncthreads();
    if (tid == 0)
        sOld = __hip_atomic_fetch_add(&cnt1[nb], 1u, __ATOMIC_ACQ_REL, __HIP_MEMORY_SCOPE_AGENT);
    __syncthreads();
    if (sOld != 3u) return;

    if (tid == 0)
        __hip_atomic_store(&cnt1[nb], 0u, __ATOMIC_RELAXED, __HIP_MEMORY_SCOPE_AGENT);
#pragma unroll
    for (int rep = 0; rep < 8; rep++) {
        int idx = rep * 256 + tid;    // 0..2047
        int b = idx >> 5, nn = idx & 31;
        int n = n0 + nn;
        float s = 0.f;
#pragma unroll
        for (int k = 0; k < 4; k++)
            s += __hip_atomic_load(&part1[((size_t)k * B + b) * NC + n],
                                   __ATOMIC_RELAXED, __HIP_MEMORY_SCOPE_AGENT);
        if (is_att) att2g[(size_t)b * AD + n] = s + bda[n];
        else {
            int d = n - AD;
            fg[(size_t)b * ED + d] = sigm(s + bfb[d]);
        }
    }
}

// ---------------------------------------------------------------------------
// kA2e: e[b,p] = relu(att1[b,p,:]+att2[b,:])·wf + bf. 256 blocks x 256:
//   b = bid>>2, ch = bid&3 -> p in [ch*49, ch*49+49). One wave per row-iter.
// ---------------------------------------------------------------------------
__global__ __launch_bounds__(256) void kA2e(const float* __restrict__ att2g,
                                            const float* __restrict__ att1,
                                            const float* __restrict__ wf,
                                            const float* __restrict__ bfv,
                                            float* __restrict__ eW) {
    int bid = blockIdx.x;
    int b = bid >> 2, ch = bid & 3;
    int tid = threadIdx.x;
    __shared__ float sa2[AD];
    __shared__ float swf[AD];
    sa2[tid] = att2g[(size_t)b * AD + tid];
    sa2[tid + 256] = att2g[(size_t)b * AD + tid + 256];
    swf[tid] = wf[tid];
    swf[tid + 256] = wf[tid + 256];
    __syncthreads();

    int w = tid >> 6, lane = tid & 63;
    float bf0 = bfv[0];
    for (int pl = w; pl < 49; pl += 4) {
        int p = ch * 49 + pl;
        const float* row = att1 + ((size_t)b * P + p) * AD + lane * 8;
        float4 u0 = *(const float4*)row;
        float4 u1 = *(const float4*)(row + 4);
        float4 s0 = *(const float4*)&sa2[lane * 8];
        float4 s1 = *(const float4*)&sa2[lane * 8 + 4];
        float4 w0 = *(const float4*)&swf[lane * 8];
        float4 w1 = *(const float4*)&swf[lane * 8 + 4];
        float acc = fmaxf(u0.x + s0.x, 0.f) * w0.x + fmaxf(u0.y + s0.y, 0.f) * w0.y +
                    fmaxf(u0.z + s0.z, 0.f) * w0.z + fmaxf(u0.w + s0.w, 0.f) * w0.w +
                    fmaxf(u1.x + s1.x, 0.f) * w1.x + fmaxf(u1.y + s1.y, 0.f) * w1.y +
                    fmaxf(u1.z + s1.z, 0.f) * w1.z + fmaxf(u1.w + s1.w, 0.f) * w1.w;
#pragma unroll
        for (int mm = 32; mm >= 1; mm >>= 1) acc += __shfl_xor(acc, mm, 64);
        if (lane == 0) eW[(size_t)b * P + p] = acc + bf0;
    }
}

// ---------------------------------------------------------------------------
// kB: per (ch,b): in-block softmax from eW (cheap 8x redundancy), then
//     awe = eo·alpha (deep in-flight), xg = fg*awe -> xT rows [E, KX).
//     ch==0 writes masked alpha to out. grid (8, B).
// ---------------------------------------------------------------------------
__global__ __launch_bounds__(256) void kB(const float* __restrict__ eo,
                                          const int* __restrict__ sidx,
                                          const float* __restrict__ eW,
                                          const float* __restrict__ fg,
                                          const int* __restrict__ dlen,
                                          float* __restrict__ xT,
                                          float* __restrict__ out, int t) {
    int b = blockIdx.y, ch = blockIdx.x, tid = threadIdx.x;
    __shared__ float se[256];
    __shared__ float red[256];
    __shared__ float sal[P];
    __shared__ float part[4][260];

    se[tid] = (tid < P) ? eW[(size_t)b * P + tid] : -1e30f;
    __syncthreads();
    red[tid] = se[tid];
    __syncthreads();
    for (int s = 128; s > 0; s >>= 1) {
        if (tid < s) red[tid] = fmaxf(red[tid], red[tid + s]);
        __syncthreads();
    }
    float mx = red[0];
    __syncthreads();
    float ex = (tid < P) ? expf(se[tid] - mx) : 0.f;
    red[tid] = ex;
    __syncthreads();
    for (int s = 128; s > 0; s >>= 1) {
        if (tid < s) red[tid] += red[tid + s];
        __syncthreads();
    }
    float inv = 1.0f / red[0];
    if (tid < P) {
        float a = ex * inv;
        sal[tid] = a;
        if (ch == 0) {
            float m = (dlen[b] > t) ? 1.f : 0.f;
            out[AOFF + ((size_t)b * TD + t) * P + tid] = a * m;
        }
    }
    __syncthreads();

    int pg = tid >> 6, lane = tid & 63;
    int d = ch * 256 + lane * 4;
    const float* base = eo + ((size_t)sidx[b] * P) * ED + d;
    float ax = 0.f, ay = 0.f, az = 0.f, aw = 0.f;
#pragma unroll 7
    for (int i = 0; i < 49; i++) {
        int p = pg + i * 4;
        float4 v = *(const float4*)(base + (size_t)p * ED);
        float a = sal[p];
        ax += v.x * a; ay += v.y * a; az += v.z * a; aw += v.w * a;
    }
    part[pg][lane * 4 + 0] = ax;
    part[pg][lane * 4 + 1] = ay;
    part[pg][lane * 4 + 2] = az;
    part[pg][lane * 4 + 3] = aw;
    __syncthreads();
    if (tid < 64) {
        int d0 = ch * 256 + tid * 4;
        float4 g = *(const float4*)(fg + (size_t)b * ED + d0);
        float s0 = part[0][tid * 4 + 0] + part[1][tid * 4 + 0] + part[2][tid * 4 + 0] + part[3][tid * 4 + 0];
        float s1 = part[0][tid * 4 + 1] + part[1][tid * 4 + 1] + part[2][tid * 4 + 1] + part[3][tid * 4 + 1];
        float s2 = part[0][tid * 4 + 2] + part[1][tid * 4 + 2] + part[2][tid * 4 + 2] + part[3][tid * 4 + 2];
        float s3 = part[0][tid * 4 + 3] + part[1][tid * 4 + 3] + part[2][tid * 4 + 3] + part[3][tid * 4 + 3];
        xT[(size_t)(E + d0 + 0) * B + b] = g.x * s0;
        xT[(size_t)(E + d0 + 1) * B + b] = g.y * s1;
        xT[(size_t)(E + d0 + 2) * B + b] = g.z * s2;
        xT[(size_t)(E + d0 + 3) * B + b] = g.w * s3;
    }
}

// ---------------------------------------------------------------------------
// kCD: gates GEMM (R6-proven: contiguous 32-col tiles, dbuf LDS + reg
//   prefetch) + fused last-arrival cell tail (cntCD[jg], 32 arrivals).
// ---------------------------------------------------------------------------
__global__ __launch_bounds__(256) void kCD(const float* __restrict__ xT,
                                           const float* __restrict__ embT_t,
                                           const float* __restrict__ xh_r,
                                           const float* __restrict__ Wih,
                                           const float* __restrict__ Whh,
                                           float* __restrict__ part,
                                           unsigned int* __restrict__ cntCD,
                                           const float* __restrict__ bih,
                                           const float* __restrict__ bhh,
                                           const float* __restrict__ h0,
                                           float* __restrict__ hseq,
                                           const float* __restrict__ cread,
                                           float* __restrict__ cwrite,
                                           const int* __restrict__ dlen,
                                           float* __restrict__ xh_w, int t) {
    int bx = blockIdx.x;
    int ks = bx >> 6, nb = bx & 63;
    int n0 = nb * 32;
    int tid = threadIdx.x;
    int tb = tid & 15, tn = tid >> 4;
    int wk = tid >> 3, wn = (tid & 7) * 4;
    __shared__ float sW[2][16][36];
    __shared__ unsigned int sOld;
    float acc[4][2] = {};
    int kbase = ks * KPER;

    auto ldw = [&](int tile) -> float4 {
        int kg = kbase + tile * 16 + wk;
        float4 wv = make_float4(0.f, 0.f, 0.f, 0.f);
        if (kg < KX) wv = *(const float4*)&Wih[(size_t)kg * NG + n0 + wn];
        else if (kg < KTOT) wv = *(const float4*)&Whh[(size_t)(kg - KX) * NG + n0 + wn];
        return wv;
    };

    float4 wreg = make_float4(0.f, 0.f, 0.f, 0.f);
    if (tid < 128) {
        wreg = ldw(0);
        *(float4*)&sW[0][wk][wn] = wreg;
    }
    __syncthreads();

    for (int tile = 0; tile < 23; tile++) {
        int cur = tile & 1, nxt = cur ^ 1;
        if (tile < 22 && tid < 128) wreg = ldw(tile + 1);
#pragma unroll
        for (int kk = 0; kk < 16; kk++) {
            int kg = kbase + tile * 16 + kk;
            float4 xv = make_float4(0.f, 0.f, 0.f, 0.f);
            if (kg < E) xv = *(const float4*)&embT_t[(size_t)kg * B + tb * 4];
            else if (kg < KX) xv = *(const float4*)&xT[(size_t)kg * B + tb * 4];
            else if (kg < KTOT) xv = *(const float4*)&xh_r[(size_t)(kg - KX) * B + tb * 4];
            float w0 = sW[cur][kk][tn * 2 + 0];
            float w1 = sW[cur][kk][tn * 2 + 1];
            acc[0][0] += xv.x * w0; acc[0][1] += xv.x * w1;
            acc[1][0] += xv.y * w0; acc[1][1] += xv.y * w1;
            acc[2][0] += xv.z * w0; acc[2][1] += xv.z * w1;
            acc[3][0] += xv.w * w0; acc[3][1] += xv.w * w1;
        }
        if (tile < 22 && tid < 128) *(float4*)&sW[nxt][wk][wn] = wreg;
        __syncthreads();
    }

#pragma unroll
    for (int i = 0; i < 4; i++)
#pragma unroll
        for (int j = 0; j < 2; j++) {
            int b = tb * 4 + i, lc = tn * 2 + j;
            __hip_atomic_store(&part[((size_t)ks * B + b) * NG + n0 + lc], acc[i][j],
                               __ATOMIC_RELAXED, __HIP_MEMORY_SCOPE_AGENT);
        }
    __syncthreads();
    int jg = nb & 15;
    if (tid == 0)
        sOld = __hip_atomic_fetch_add(&cntCD[jg], 1u, __ATOMIC_ACQ_REL, __HIP_MEMORY_SCOPE_AGENT);
    __syncthreads();
    if (sOld != 31u) return;

    if (tid == 0)
        __hip_atomic_store(&cntCD[jg], 0u, __ATOMIC_RELAXED, __HIP_MEMORY_SCOPE_AGENT);

    const float* holds = (t == 0) ? h0 : (hseq + (size_t)(t - 1) * B * DD);
#pragma unroll
    for (int rep = 0; rep < 8; rep++) {
        int idx = rep * 256 + tid;   // 0..2047
        int bb = idx >> 5;           // 0..63
        int jj = idx & 31;           // 0..31
        int j = jg * 32 + jj;
        float g4[4];
#pragma unroll
        for (int g = 0; g < 4; g++) {
            float gv = bih[g * DD + j] + bhh[g * DD + j];
#pragma unroll
            for (int s = 0; s < KSPLIT; s++)
                gv += __hip_atomic_load(&part[((size_t)s * B + bb) * NG + g * 512 + j],
                                        __ATOMIC_RELAXED, __HIP_MEMORY_SCOPE_AGENT);
            g4[g] = gv;
        }
        float cold = cread[(size_t)bb * DD + j];
        float hold = holds[(size_t)bb * DD + j];
        float cnew = sigm(g4[1]) * cold + sigm(g4[0]) * tanhf(g4[2]);
        float hnew = sigm(g4[3]) * tanhf(cnew);
        bool m = dlen[bb] > t;
        float h2 = m ? hnew : hold;
        float c2 = m ? cnew : cold;
        hseq[(size_t)t * B * DD + (size_t)bb * DD + j] = h2;
        cwrite[(size_t)bb * DD + j] = c2;
        xh_w[(size_t)j * B + bb] = h2;
    }
}

// ---------------------------------------------------------------------------
// K4: batched preds GEMM: out[b,t,v] = mask * (hseq[t,b,:]@Wfc + bfc)
// ---------------------------------------------------------------------------
__global__ __launch_bounds__(256) void k_predsall(const float* __restrict__ hseq,
                                                  const float* __restrict__ Wfc,
                                                  const float* __restrict__ bfc,
                                                  const int* __restrict__ dlen,
                                                  float* __restrict__ out) {
    int t = blockIdx.x;
    int n0 = blockIdx.y * 64;
    int tid = threadIdx.x;
    int tx = tid & 15, ty = tid >> 4;
    __shared__ float sA[16][68];
    __shared__ float sB[16][68];
    float acc[4][4] = {};
    const float* A = hseq + (size_t)t * B * DD;

    for (int k0 = 0; k0 < DD; k0 += 16) {
        {
            int b = tid >> 2, q = tid & 3;
            float4 hv = *(const float4*)(A + (size_t)b * DD + k0 + q * 4);
            sA[q * 4 + 0][b] = hv.x;
            sA[q * 4 + 1][b] = hv.y;
            sA[q * 4 + 2][b] = hv.z;
            sA[q * 4 + 3][b] = hv.w;
        }
        {
            int kk = tid >> 4, nn = (tid & 15) * 4;
            int c = n0 + nn;
            const float* wrow = Wfc + (size_t)(k0 + kk) * V;
            float4 wv;
            if (c + 3 < V) wv = *(const float4*)(wrow + c);
            else {
                wv.x = (c + 0 < V) ? wrow[c + 0] : 0.f;
                wv.y = (c + 1 < V) ? wrow[c + 1] : 0.f;
                wv.z = (c + 2 < V) ? wrow[c + 2] : 0.f;
                wv.w = (c + 3 < V) ? wrow[c + 3] : 0.f;
            }
            *(float4*)&sB[kk][nn] = wv;
        }
        __syncthreads();
#pragma unroll
        for (int kk = 0; kk < 16; kk++) {
            float4 a4 = *(const float4*)&sA[kk][ty * 4];
            float4 b4 = *(const float4*)&sB[kk][tx * 4];
            float av_[4] = {a4.x, a4.y, a4.z, a4.w};
            float bv_[4] = {b4.x, b4.y, b4.z, b4.w};
#pragma unroll
            for (int i = 0; i < 4; i++)
#pragma unroll
                for (int j = 0; j < 4; j++) acc[i][j] += av_[i] * bv_[j];
        }
        __syncthreads();
    }
#pragma unroll
    for (int i = 0; i < 4; i++) {
        int b = ty * 4 + i;
        bool m = dlen[b] > t;
#pragma unroll
        for (int j = 0; j < 4; j++) {
            int n = n0 + tx * 4 + j;
            if (n < V)
                out[POFF + ((size_t)b * TD + t) * V + n] = m ? (acc[i][j] + bfc[n]) : 0.f;
        }
    }
}

// ---------------------------------------------------------------------------
extern "C" void kernel_launch(void* const* d_in, const int* in_sizes, int n_in,
                              void* d_out, int out_size, void* d_ws, size_t ws_size,
                              hipStream_t stream) {
    const float* eo    = (const float*)d_in[0];
    const int*   caps  = (const int*)d_in[1];
    const int*   lens  = (const int*)d_in[2];
    const float* emb   = (const float*)d_in[3];
    const float* Wea   = (const float*)d_in[4];
    const float* bea   = (const float*)d_in[5];
    const float* Wda   = (const float*)d_in[6];
    const float* bda   = (const float*)d_in[7];
    const float* wfull = (const float*)d_in[8];
    const float* bfull = (const float*)d_in[9];
    const float* Wih_  = (const float*)d_in[10];
    const float* bih_  = (const float*)d_in[11];
    const float* Wic   = (const float*)d_in[12];
    const float* bic   = (const float*)d_in[13];
    const float* Wfb   = (const float*)d_in[14];
    const float* bfb   = (const float*)d_in[15];
    const float* Wih   = (const float*)d_in[16];
    const float* bih   = (const float*)d_in[17];
    const float* Whh   = (const float*)d_in[18];
    const float* bhh   = (const float*)d_in[19];
    const float* Wfc   = (const float*)d_in[20];
    const float* bfc   = (const float*)d_in[21];
    float* out = (float*)d_out;

    char* w = (char*)d_ws;
    auto carve = [&](size_t bytes) -> void* {
        void* p = (void*)w;
        w += (bytes + 255) & ~(size_t)255;
        return p;
    };
    int* sidx      = (int*)carve(B * 4);
    int* dlen      = (int*)carve(B * 4);
    int* caps_s    = (int*)carve((size_t)B * T * 4);
    unsigned int* cnt = (unsigned int*)carve(128 * 4);
    float* mean_eo = (float*)carve((size_t)B * ED * 4);
    float* h0      = (float*)carve((size_t)B * DD * 4);
    float* cb0     = (float*)carve((size_t)B * DD * 4);
    float* cb1     = (float*)carve((size_t)B * DD * 4);
    float* att1    = (float*)carve((size_t)B * P * AD * 4);
    float* eWb     = (float*)carve((size_t)B * P * 4);
    float* att2g   = (float*)carve((size_t)B * AD * 4);
    float* fg      = (float*)carve((size_t)B * ED * 4);
    float* xT      = (float*)carve((size_t)(KTOT + DD) * B * 4);  // + extra h slot
    float* part    = (float*)carve((size_t)KSPLIT * B * NG * 4);
    float* part1   = (float*)carve((size_t)4 * B * NC * 4);
    float* hseq    = (float*)carve((size_t)TD * B * DD * 4);
    float* embT    = (float*)carve((size_t)TD * E * B * 4);
    float* cb[2] = {cb0, cb1};
    unsigned int* cnt1  = cnt;        // 80 entries for kA1
    unsigned int* cntCD = cnt + 96;   // 16 entries for kCD

    k_sort<<<1, 64, 0, stream>>>(lens, caps, sidx, dlen, caps_s, cnt, out);
    k_emball<<<dim3(TD, 5), 256, 0, stream>>>(emb, caps_s, embT);
    k_mean<<<dim3(ED / 256, B), 256, 0, stream>>>(eo, sidx, mean_eo);
    k_init<<<(B * DD) / 256, 256, 0, stream>>>(mean_eo, Wih_, bih_, Wic, bic, h0, cb1, xT);
    k_att1<<<dim3((B * P) / 64, AD / 64), 256, 0, stream>>>(eo, Wea, bea, sidx, att1);

    // h(t) -> xT h-slot[t&1]; h(-1)=h0 in slot 1. c(t) -> cb[t&1]; c(-1)=c0 in cb1.
    for (int t = 0; t < TD; t++) {
        const float* hprev = (t == 0) ? h0 : (hseq + (size_t)(t - 1) * B * DD);
        kA1<<<320, 256, 0, stream>>>(hprev, Wda, Wfb, bda, bfb, part1, cnt1, att2g, fg);
        kA2e<<<256, 256, 0, stream>>>(att2g, att1, wfull, bfull, eWb);
        kB<<<dim3(8, B), 256, 0, stream>>>(eo, sidx, eWb, fg, dlen, xT, out, t);
        const float* xh_r = xT + (size_t)(KX + ((t + 1) & 1) * DD) * B;
        float*       xh_w = xT + (size_t)(KX + (t & 1) * DD) * B;
        kCD<<<512, 256, 0, stream>>>(xT, embT + (size_t)t * E * B, xh_r, Wih, Whh, part, cntCD,
                                     bih, bhh, h0, hseq, cb[(t + 1) & 1], cb[t & 1], dlen, xh_w, t);
    }
    k_predsall<<<dim3(TD, 16), 256, 0, stream>>>(hseq, Wfc, bfc, dlen, out);
}